// Round 1
// baseline (333.439 us; speedup 1.0000x reference)
//
#include <hip/hip_runtime.h>
#include <hip/hip_bf16.h>
#include <cstdint>
#include <cmath>

typedef __bf16 bf16_t;
typedef __bf16 bf16x8 __attribute__((ext_vector_type(8)));
typedef __bf16 bf16x4 __attribute__((ext_vector_type(4)));
typedef float floatx4 __attribute__((ext_vector_type(4)));

#define MB ((size_t)1 << 20)

// async global->LDS, 16B per lane. LDS dest must be wave-uniform base + lane*16.
static __device__ __forceinline__ void async_load16(const void* g, void* l) {
    __builtin_amdgcn_global_load_lds(
        (const __attribute__((address_space(1))) uint32_t*)(uintptr_t)g,
        (__attribute__((address_space(3))) uint32_t*)(uint32_t)(uintptr_t)l,
        16, 0, 0);
}

// ---------------- elementwise / prep kernels ----------------

__global__ void cast_x_kernel(const float* __restrict__ x, bf16_t* __restrict__ xb) {
    int i = blockIdx.x * 256 + threadIdx.x;          // one float4 per thread
    float4 v = ((const float4*)x)[i];
    bf16x4 o;
    o[0] = (bf16_t)v.x; o[1] = (bf16_t)v.y; o[2] = (bf16_t)v.z; o[3] = (bf16_t)v.w;
    ((bf16x4*)xb)[i] = o;
}

// colsum[d] = sum_i exp(wv[i][d]); partial rows per block, atomic combine.
__global__ void prep_colsum(const float* __restrict__ wv, float* __restrict__ cs) {
    int d  = blockIdx.x * 256 + threadIdx.x;   // gridDim.x = 4
    int r0 = blockIdx.y * 64;                  // gridDim.y = 16
    float s = 0.f;
    for (int i = 0; i < 64; i++) s += __expf(wv[(r0 + i) * 1024 + d]);
    atomicAdd(&cs[d], s);
}

// w3T[e][d] = exp(wv[e][d]) / (colsum[d]*1024)  — elementwise on wv (no transpose!)
__global__ void prep_w3(const float* __restrict__ wv, const float* __restrict__ cs,
                        bf16_t* __restrict__ w3T) {
    int idx = blockIdx.x * 256 + threadIdx.x;  // 4096 blocks
    int d = idx & 1023;
    w3T[idx] = (bf16_t)(__expf(wv[idx]) / (cs[d] * 1024.0f));
}

// WT[j][d] = W[d][j], f32 -> bf16, 32x32 LDS tile transpose
__global__ void transpose_w(const float* __restrict__ W, bf16_t* __restrict__ WT) {
    __shared__ float tile[32][33];
    int tx = threadIdx.x & 31, ty = threadIdx.x >> 5;   // 8 rows of 32
    int c0 = blockIdx.x * 32, r0 = blockIdx.y * 32;
    #pragma unroll
    for (int i = 0; i < 4; i++)
        tile[ty + i * 8][tx] = W[(r0 + ty + i * 8) * 1024 + c0 + tx];
    __syncthreads();
    #pragma unroll
    for (int i = 0; i < 4; i++)
        WT[(long)(c0 + ty + i * 8) * 1024 + r0 + tx] = (bf16_t)tile[tx][ty + i * 8];
}

// vp[token][e] *= 1/L[token]   (in place, bf16, 4 elems/thread)
__global__ void scale_vp(bf16_t* __restrict__ vp, const float* __restrict__ L) {
    int i = blockIdx.x * 256 + threadIdx.x;   // 8192 blocks
    int row = (i * 4) >> 10;
    float rl = 1.0f / L[row];
    bf16x4 v = ((bf16x4*)vp)[i];
    #pragma unroll
    for (int j = 0; j < 4; j++) v[j] = (bf16_t)((float)v[j] * rl);
    ((bf16x4*)vp)[i] = v;
}

// vpT[b][e][m] = vp[b*2048+m][e]
__global__ void transpose_vp(const bf16_t* __restrict__ vp, bf16_t* __restrict__ vpT) {
    __shared__ bf16_t tile[32][33];
    int tx = threadIdx.x & 31, ty = threadIdx.x >> 5;
    int e0 = blockIdx.x * 32;   // 32
    int m0 = blockIdx.y * 32;   // 256 (global token)
    #pragma unroll
    for (int i = 0; i < 4; i++)
        tile[ty + i * 8][tx] = vp[(long)(m0 + ty + i * 8) * 1024 + e0 + tx];
    __syncthreads();
    int b = m0 >> 11, ml = m0 & 2047;
    #pragma unroll
    for (int i = 0; i < 4; i++)
        vpT[((long)(b * 1024 + e0 + ty + i * 8)) * 2048 + ml + tx] = tile[tx][ty + i * 8];
}

// ---------------- NT GEMM: C[M,N] = A[M,K] * B[N,K]^T  (bf16 in, fp32 acc) ----------------
// EPI 0: store bf16
// EPI 2: p = exp(acc*scaleExp); store bf16 P; column sums atomicAdd -> Lout
// EPI 3: store f32: acc - Vp[row,col]*Lrow[row]
template <int EPI>
__global__ __launch_bounds__(256) void gemm_nt(
    const bf16_t* __restrict__ A, const bf16_t* __restrict__ B, void* __restrict__ C,
    const float* __restrict__ Lrow, float* __restrict__ Lout, const bf16_t* __restrict__ Vp,
    int M, int N, int K,
    long aBatch, long bBatch, long cBatch, int lBatch, float scaleExp)
{
    __shared__ __align__(16) bf16_t ldsA[128 * 32];
    __shared__ __align__(16) bf16_t ldsB[128 * 32];
    const int t = threadIdx.x;
    const int z = blockIdx.z;
    const bf16_t* Ab = A + (long)z * aBatch + (long)blockIdx.y * 128 * K;
    const bf16_t* Bb = B + (long)z * bBatch + (long)blockIdx.x * 128 * K;
    const int r  = t >> 2;          // 0..63
    const int kc = (t & 3) * 8;     // k element offset within 32
    const bf16_t* ag0 = Ab + (long)r * K + kc;
    const bf16_t* bg0 = Bb + (long)r * K + kc;
    bf16_t* la = ldsA + t * 8;      // byte offset t*16 (lane-contiguous per wave)
    bf16_t* lb = ldsB + t * 8;
    const int lane = t & 63, wave = t >> 6;
    const int wm = (wave >> 1) * 64, wn = (wave & 1) * 64;
    const int fr = lane & 15;
    const int fk = (lane >> 4) * 8;

    floatx4 zero = {0.f, 0.f, 0.f, 0.f};
    floatx4 acc[4][4];
    #pragma unroll
    for (int i = 0; i < 4; i++)
        #pragma unroll
        for (int j = 0; j < 4; j++) acc[i][j] = zero;

    for (int k0 = 0; k0 < K; k0 += 32) {
        __syncthreads();
        async_load16(ag0 + k0, la);
        async_load16(ag0 + (long)64 * K + k0, la + 64 * 32);
        async_load16(bg0 + k0, lb);
        async_load16(bg0 + (long)64 * K + k0, lb + 64 * 32);
        __syncthreads();   // compiler emits s_waitcnt vmcnt(0) before barrier
        bf16x8 af[4], bfr[4];
        #pragma unroll
        for (int i = 0; i < 4; i++)
            af[i] = *(const bf16x8*)(ldsA + (wm + i * 16 + fr) * 32 + fk);
        #pragma unroll
        for (int j = 0; j < 4; j++)
            bfr[j] = *(const bf16x8*)(ldsB + (wn + j * 16 + fr) * 32 + fk);
        #pragma unroll
        for (int i = 0; i < 4; i++)
            #pragma unroll
            for (int j = 0; j < 4; j++)
                acc[i][j] = __builtin_amdgcn_mfma_f32_16x16x32_bf16(af[i], bfr[j], acc[i][j], 0, 0, 0);
    }

    // C/D layout: col = lane&15, row = (lane>>4)*4 + reg  [m89-verified]
    const int rq = (lane >> 4) * 4;
    const long rowBase = (long)blockIdx.y * 128 + wm;
    const int colBase = blockIdx.x * 128 + wn;

    if constexpr (EPI == 0) {
        bf16_t* Cb = (bf16_t*)C + (long)z * cBatch;
        #pragma unroll
        for (int mi = 0; mi < 4; mi++)
            #pragma unroll
            for (int rr = 0; rr < 4; rr++) {
                long row = rowBase + mi * 16 + rq + rr;
                #pragma unroll
                for (int ni = 0; ni < 4; ni++)
                    Cb[row * N + colBase + ni * 16 + fr] = (bf16_t)acc[mi][ni][rr];
            }
    } else if constexpr (EPI == 2) {
        bf16_t* Cb = (bf16_t*)C + (long)z * cBatch;
        float csum[4] = {0.f, 0.f, 0.f, 0.f};
        #pragma unroll
        for (int mi = 0; mi < 4; mi++)
            #pragma unroll
            for (int rr = 0; rr < 4; rr++) {
                long row = rowBase + mi * 16 + rq + rr;
                #pragma unroll
                for (int ni = 0; ni < 4; ni++) {
                    float p = __expf(acc[mi][ni][rr] * scaleExp);
                    Cb[row * N + colBase + ni * 16 + fr] = (bf16_t)p;
                    csum[ni] += p;
                }
            }
        #pragma unroll
        for (int ni = 0; ni < 4; ni++) {
            float v = csum[ni];
            v += __shfl_xor(v, 16);
            v += __shfl_xor(v, 32);
            if (lane < 16)
                atomicAdd(Lout + (long)z * lBatch + colBase + ni * 16 + lane, v);
        }
    } else {  // EPI == 3
        float* Co = (float*)C + (long)z * cBatch;
        const bf16_t* Vb = Vp + (long)z * cBatch;
        #pragma unroll
        for (int mi = 0; mi < 4; mi++)
            #pragma unroll
            for (int rr = 0; rr < 4; rr++) {
                long row = rowBase + mi * 16 + rq + rr;
                float Lr = Lrow[z * lBatch + (int)row];
                #pragma unroll
                for (int ni = 0; ni < 4; ni++) {
                    int col = colBase + ni * 16 + fr;
                    Co[row * N + col] = acc[mi][ni][rr] - (float)Vb[row * N + col] * Lr;
                }
            }
    }
}

// ---------------- launch ----------------

extern "C" void kernel_launch(void* const* d_in, const int* in_sizes, int n_in,
                              void* d_out, int out_size, void* d_ws, size_t ws_size,
                              hipStream_t stream) {
    // setup_inputs order: x, wk, wq, wv
    const float* x  = (const float*)d_in[0];
    const float* wk = (const float*)d_in[1];
    const float* wq = (const float*)d_in[2];
    const float* wv = (const float*)d_in[3];
    float* out = (float*)d_out;

    char* ws = (char*)d_ws;
    // Workspace layout (80 MB + 36 KB), with lifetime-based overlap:
    //   [0,16M)  xb (dead after vraw GEMM)  --> reused as start of P
    //   [16,22M) wqT/wkT/w3T (dead after proj GEMMs) --> inside P
    //   [0,32M)  P  (written in pass A, after xb/weights dead)
    //   [32,48M) q  (dead after pass A)  --> reused as vpT
    //   [48,64M) k
    //   [64,80M) vraw -> vp (in place)
    //   [80M,..) L (32KB) + colsum (4KB)
    bf16_t* P   = (bf16_t*)(ws + 0);
    bf16_t* xb  = (bf16_t*)(ws + 0);
    bf16_t* wqT = (bf16_t*)(ws + 16 * MB);
    bf16_t* wkT = (bf16_t*)(ws + 18 * MB);
    bf16_t* w3T = (bf16_t*)(ws + 20 * MB);
    bf16_t* q   = (bf16_t*)(ws + 32 * MB);
    bf16_t* k   = (bf16_t*)(ws + 48 * MB);
    bf16_t* vp  = (bf16_t*)(ws + 64 * MB);
    bf16_t* vpT = (bf16_t*)(ws + 32 * MB);
    float*  L   = (float*)(ws + 80 * MB);
    // cs = L + 8192 floats

    const float scale = 0.022097086912079608f;  // 2048^-0.5

    hipMemsetAsync(L, 0, 36864, stream);  // L (8192 f32) + colsum (1024 f32)

    cast_x_kernel<<<8192, 256, 0, stream>>>(x, xb);
    prep_colsum<<<dim3(4, 16), 256, 0, stream>>>(wv, L + 8192);
    prep_w3<<<4096, 256, 0, stream>>>(wv, L + 8192, w3T);
    transpose_w<<<dim3(32, 32), 256, 0, stream>>>(wq, wqT);
    transpose_w<<<dim3(32, 32), 256, 0, stream>>>(wk, wkT);

    // projections: q = x@wq, k = x@wk, vraw = x@wv_stoch   [8192 x 1024 x 1024]
    gemm_nt<0><<<dim3(8, 64, 1), 256, 0, stream>>>(xb, wqT, q, nullptr, nullptr, nullptr,
        8192, 1024, 1024, 0, 0, 0, 0, 0.f);
    gemm_nt<0><<<dim3(8, 64, 1), 256, 0, stream>>>(xb, wkT, k, nullptr, nullptr, nullptr,
        8192, 1024, 1024, 0, 0, 0, 0, 0.f);
    gemm_nt<0><<<dim3(8, 64, 1), 256, 0, stream>>>(xb, w3T, vp, nullptr, nullptr, nullptr,
        8192, 1024, 1024, 0, 0, 0, 0, 0.f);

    // pass A: P[b,n,m] = exp(scale * q.k), column sums -> L[b,m]
    gemm_nt<2><<<dim3(16, 16, 4), 256, 0, stream>>>(q, k, P, nullptr, L, nullptr,
        2048, 2048, 1024, (long)2048 * 1024, (long)2048 * 1024, (long)2048 * 2048, 2048, scale);

    // v' = vraw / L ; transpose for NT pass B
    scale_vp<<<8192, 256, 0, stream>>>(vp, L);
    transpose_vp<<<dim3(32, 256), 256, 0, stream>>>(vp, vpT);

    // pass B: out[b,n,e] = P@v' - v'[n,e]*L[n]
    gemm_nt<3><<<dim3(8, 16, 4), 256, 0, stream>>>(P, vpT, out, L, nullptr, vp,
        2048, 1024, 2048, (long)2048 * 2048, (long)1024 * 2048, (long)2048 * 1024, 2048, 0.f);
}

// Round 2
// 310.397 us; speedup vs baseline: 1.0742x; 1.0742x over previous
//
#include <hip/hip_runtime.h>
#include <hip/hip_bf16.h>
#include <cstdint>
#include <cmath>

typedef __bf16 bf16_t;
typedef __bf16 bf16x8 __attribute__((ext_vector_type(8)));
typedef __bf16 bf16x4 __attribute__((ext_vector_type(4)));
typedef float floatx4 __attribute__((ext_vector_type(4)));

#define MB ((size_t)1 << 20)

// async global->LDS, 16B per lane. LDS dest must be wave-uniform base + lane*16.
static __device__ __forceinline__ void async_load16(const void* g, void* l) {
    __builtin_amdgcn_global_load_lds(
        (const __attribute__((address_space(1))) uint32_t*)(uintptr_t)g,
        (__attribute__((address_space(3))) uint32_t*)(uint32_t)(uintptr_t)l,
        16, 0, 0);
}

// ---------------- elementwise / prep kernels ----------------

__global__ void cast_x_kernel(const float* __restrict__ x, bf16_t* __restrict__ xb) {
    int i = blockIdx.x * 256 + threadIdx.x;          // one float4 per thread
    float4 v = ((const float4*)x)[i];
    bf16x4 o;
    o[0] = (bf16_t)v.x; o[1] = (bf16_t)v.y; o[2] = (bf16_t)v.z; o[3] = (bf16_t)v.w;
    ((bf16x4*)xb)[i] = o;
}

// colsum[d] = sum_i exp(wv[i][d]); partial rows per block, atomic combine.
__global__ void prep_colsum(const float* __restrict__ wv, float* __restrict__ cs) {
    int d  = blockIdx.x * 256 + threadIdx.x;   // gridDim.x = 4
    int r0 = blockIdx.y * 64;                  // gridDim.y = 16
    float s = 0.f;
    for (int i = 0; i < 64; i++) s += __expf(wv[(r0 + i) * 1024 + d]);
    atomicAdd(&cs[d], s);
}

// w3T[e][d] = exp(wv[e][d]) / (colsum[d]*1024)  — elementwise on wv (no transpose!)
__global__ void prep_w3(const float* __restrict__ wv, const float* __restrict__ cs,
                        bf16_t* __restrict__ w3T) {
    int idx = blockIdx.x * 256 + threadIdx.x;  // 4096 blocks
    int d = idx & 1023;
    w3T[idx] = (bf16_t)(__expf(wv[idx]) / (cs[d] * 1024.0f));
}

// WT[j][d] = W[d][j], f32 -> bf16, 32x32 LDS tile transpose
__global__ void transpose_w(const float* __restrict__ W, bf16_t* __restrict__ WT) {
    __shared__ float tile[32][33];
    int tx = threadIdx.x & 31, ty = threadIdx.x >> 5;   // 8 rows of 32
    int c0 = blockIdx.x * 32, r0 = blockIdx.y * 32;
    #pragma unroll
    for (int i = 0; i < 4; i++)
        tile[ty + i * 8][tx] = W[(r0 + ty + i * 8) * 1024 + c0 + tx];
    __syncthreads();
    #pragma unroll
    for (int i = 0; i < 4; i++)
        WT[(long)(c0 + ty + i * 8) * 1024 + r0 + tx] = (bf16_t)tile[tx][ty + i * 8];
}

// vp[token][e] *= 1/L[token]   (in place, bf16, 4 elems/thread)
__global__ void scale_vp(bf16_t* __restrict__ vp, const float* __restrict__ L) {
    int i = blockIdx.x * 256 + threadIdx.x;   // 8192 blocks
    int row = (i * 4) >> 10;
    float rl = 1.0f / L[row];
    bf16x4 v = ((bf16x4*)vp)[i];
    #pragma unroll
    for (int j = 0; j < 4; j++) v[j] = (bf16_t)((float)v[j] * rl);
    ((bf16x4*)vp)[i] = v;
}

// vpT[b][e][m] = vp[b*2048+m][e]
__global__ void transpose_vp(const bf16_t* __restrict__ vp, bf16_t* __restrict__ vpT) {
    __shared__ bf16_t tile[32][33];
    int tx = threadIdx.x & 31, ty = threadIdx.x >> 5;
    int e0 = blockIdx.x * 32;   // 32
    int m0 = blockIdx.y * 32;   // 256 (global token)
    #pragma unroll
    for (int i = 0; i < 4; i++)
        tile[ty + i * 8][tx] = vp[(long)(m0 + ty + i * 8) * 1024 + e0 + tx];
    __syncthreads();
    int b = m0 >> 11, ml = m0 & 2047;
    #pragma unroll
    for (int i = 0; i < 4; i++)
        vpT[((long)(b * 1024 + e0 + ty + i * 8)) * 2048 + ml + tx] = tile[tx][ty + i * 8];
}

// ---------------- NT GEMM: C[M,N] = A[M,K] * B[N,K]^T  (bf16 in, fp32 acc) ----------------
// LDS layout is XOR-swizzled: chunk c (16B) of row r is stored at chunk-position
// c ^ ((r>>1)&3). For a quarter-wave reading 16 consecutive rows at fixed global
// chunk q, the bank quad index 4*(row&1) + (q ^ ((row>>1)&3)) covers all 8 quads
// over 8 rows -> 2-way aliasing only (free) instead of 4-way.
// EPI 0: store bf16, 3 output buffers selected by blockIdx.x>>3 (merged QKV)
// EPI 2: p = exp(acc*scaleExp); store bf16 P; column sums atomicAdd -> Lout
// EPI 3: store f32: acc - Vp[row,col]*Lrow[row]
template <int EPI>
__global__ __launch_bounds__(256) void gemm_nt(
    const bf16_t* __restrict__ A, const bf16_t* __restrict__ B, void* __restrict__ C,
    bf16_t* __restrict__ C1, bf16_t* __restrict__ C2,
    const float* __restrict__ Lrow, float* __restrict__ Lout, const bf16_t* __restrict__ Vp,
    int N, int K,
    long aBatch, long bBatch, long cBatch, int lBatch, float scaleExp)
{
    __shared__ __align__(16) bf16_t ldsA[128 * 32];
    __shared__ __align__(16) bf16_t ldsB[128 * 32];
    const int t = threadIdx.x;
    const int z = blockIdx.z;
    const bf16_t* Ab = A + (long)z * aBatch + (long)blockIdx.y * 128 * K;
    const bf16_t* Bb = B + (long)z * bBatch + (long)blockIdx.x * 128 * K;
    const int r  = t >> 2;                         // 0..63 (row pair loaded by this thread)
    const int cg = (t & 3) ^ ((t >> 3) & 3);       // swizzled global chunk for LDS slot t&3
    const bf16_t* ag0 = Ab + (long)r * K + cg * 8;
    const bf16_t* bg0 = Bb + (long)r * K + cg * 8;
    bf16_t* la = ldsA + t * 8;      // byte offset t*16 (lane-contiguous per wave)
    bf16_t* lb = ldsB + t * 8;
    const int lane = t & 63, wave = t >> 6;
    const int wm = (wave >> 1) * 64, wn = (wave & 1) * 64;
    const int fr = lane & 15;
    const int fkp = (((lane >> 4) ^ ((fr >> 1) & 3)) * 8);   // swizzled read chunk

    floatx4 zero = {0.f, 0.f, 0.f, 0.f};
    floatx4 acc[4][4];
    #pragma unroll
    for (int i = 0; i < 4; i++)
        #pragma unroll
        for (int j = 0; j < 4; j++) acc[i][j] = zero;

    for (int k0 = 0; k0 < K; k0 += 32) {
        __syncthreads();
        async_load16(ag0 + k0, la);
        async_load16(ag0 + (long)64 * K + k0, la + 64 * 32);
        async_load16(bg0 + k0, lb);
        async_load16(bg0 + (long)64 * K + k0, lb + 64 * 32);
        __syncthreads();   // compiler emits s_waitcnt vmcnt(0) before barrier
        bf16x8 af[4], bfr[4];
        #pragma unroll
        for (int i = 0; i < 4; i++)
            af[i] = *(const bf16x8*)(ldsA + (wm + i * 16 + fr) * 32 + fkp);
        #pragma unroll
        for (int j = 0; j < 4; j++)
            bfr[j] = *(const bf16x8*)(ldsB + (wn + j * 16 + fr) * 32 + fkp);
        #pragma unroll
        for (int i = 0; i < 4; i++)
            #pragma unroll
            for (int j = 0; j < 4; j++)
                acc[i][j] = __builtin_amdgcn_mfma_f32_16x16x32_bf16(af[i], bfr[j], acc[i][j], 0, 0, 0);
    }

    // C/D layout: col = lane&15, row = (lane>>4)*4 + reg  [m89-verified]
    const int rq = (lane >> 4) * 4;
    const long rowBase = (long)blockIdx.y * 128 + wm;
    const int colBase = blockIdx.x * 128 + wn;

    if constexpr (EPI == 0) {
        // merged QKV: blockIdx.x in [0,24), output buffer = x>>3, col tile = x&7
        int sel = blockIdx.x >> 3;
        bf16_t* Cb = sel == 0 ? (bf16_t*)C : (sel == 1 ? C1 : C2);
        const int cB = (blockIdx.x & 7) * 128 + wn;
        #pragma unroll
        for (int mi = 0; mi < 4; mi++)
            #pragma unroll
            for (int rr = 0; rr < 4; rr++) {
                long row = rowBase + mi * 16 + rq + rr;
                #pragma unroll
                for (int ni = 0; ni < 4; ni++)
                    Cb[row * N + cB + ni * 16 + fr] = (bf16_t)acc[mi][ni][rr];
            }
    } else if constexpr (EPI == 2) {
        bf16_t* Cb = (bf16_t*)C + (long)z * cBatch;
        float csum[4] = {0.f, 0.f, 0.f, 0.f};
        #pragma unroll
        for (int mi = 0; mi < 4; mi++)
            #pragma unroll
            for (int rr = 0; rr < 4; rr++) {
                long row = rowBase + mi * 16 + rq + rr;
                #pragma unroll
                for (int ni = 0; ni < 4; ni++) {
                    float p = __expf(acc[mi][ni][rr] * scaleExp);
                    Cb[row * N + colBase + ni * 16 + fr] = (bf16_t)p;
                    csum[ni] += p;
                }
            }
        #pragma unroll
        for (int ni = 0; ni < 4; ni++) {
            float v = csum[ni];
            v += __shfl_xor(v, 16);
            v += __shfl_xor(v, 32);
            if (lane < 16)
                atomicAdd(Lout + (long)z * lBatch + colBase + ni * 16 + lane, v);
        }
    } else {  // EPI == 3
        float* Co = (float*)C + (long)z * cBatch;
        const bf16_t* Vb = Vp + (long)z * cBatch;
        #pragma unroll
        for (int mi = 0; mi < 4; mi++)
            #pragma unroll
            for (int rr = 0; rr < 4; rr++) {
                long row = rowBase + mi * 16 + rq + rr;
                float Lr = Lrow[z * lBatch + (int)row];
                #pragma unroll
                for (int ni = 0; ni < 4; ni++) {
                    int col = colBase + ni * 16 + fr;
                    Co[row * N + col] = acc[mi][ni][rr] - (float)Vb[row * N + col] * Lr;
                }
            }
    }
}

// ---------------- launch ----------------

extern "C" void kernel_launch(void* const* d_in, const int* in_sizes, int n_in,
                              void* d_out, int out_size, void* d_ws, size_t ws_size,
                              hipStream_t stream) {
    // setup_inputs order: x, wk, wq, wv
    const float* x  = (const float*)d_in[0];
    const float* wk = (const float*)d_in[1];
    const float* wq = (const float*)d_in[2];
    const float* wv = (const float*)d_in[3];
    float* out = (float*)d_out;

    char* ws = (char*)d_ws;
    // Workspace layout (80 MB + 36 KB), with lifetime-based overlap:
    //   [0,16M)  xb (dead after QKV GEMM)  --> reused as start of P
    //   [16,22M) wqT|wkT|w3T contiguous (= 3072x1024 concat B; dead after QKV) --> inside P
    //   [0,32M)  P  (written in pass A, after xb/weights dead)
    //   [32,48M) q  (dead after pass A)  --> reused as vpT
    //   [48,64M) k
    //   [64,80M) vraw -> vp (in place)
    //   [80M,..) L (32KB) + colsum (4KB)
    bf16_t* P   = (bf16_t*)(ws + 0);
    bf16_t* xb  = (bf16_t*)(ws + 0);
    bf16_t* wqT = (bf16_t*)(ws + 16 * MB);   // base of the 3072x1024 concat
    bf16_t* wkT = (bf16_t*)(ws + 18 * MB);
    bf16_t* w3T = (bf16_t*)(ws + 20 * MB);
    bf16_t* q   = (bf16_t*)(ws + 32 * MB);
    bf16_t* k   = (bf16_t*)(ws + 48 * MB);
    bf16_t* vp  = (bf16_t*)(ws + 64 * MB);
    bf16_t* vpT = (bf16_t*)(ws + 32 * MB);
    float*  L   = (float*)(ws + 80 * MB);
    // cs = L + 8192 floats

    const float scale = 0.022097086912079608f;  // 2048^-0.5

    hipMemsetAsync(L, 0, 36864, stream);  // L (8192 f32) + colsum (1024 f32)

    cast_x_kernel<<<8192, 256, 0, stream>>>(x, xb);
    prep_colsum<<<dim3(4, 16), 256, 0, stream>>>(wv, L + 8192);
    prep_w3<<<4096, 256, 0, stream>>>(wv, L + 8192, w3T);
    transpose_w<<<dim3(32, 32), 256, 0, stream>>>(wq, wqT);
    transpose_w<<<dim3(32, 32), 256, 0, stream>>>(wk, wkT);

    // merged projections: [q|k|vraw] = x @ [wq|wk|wv_stoch]   8192 x 3072 x 1024
    gemm_nt<0><<<dim3(24, 64, 1), 256, 0, stream>>>(xb, wqT, q, k, vp,
        nullptr, nullptr, nullptr, 1024, 1024, 0, 0, 0, 0, 0.f);

    // pass A: P[b,n,m] = exp(scale * q.k), column sums -> L[b,m]
    gemm_nt<2><<<dim3(16, 16, 4), 256, 0, stream>>>(q, k, P, nullptr, nullptr,
        nullptr, L, nullptr, 2048, 1024,
        (long)2048 * 1024, (long)2048 * 1024, (long)2048 * 2048, 2048, scale);

    // v' = vraw / L ; transpose for NT pass B
    scale_vp<<<8192, 256, 0, stream>>>(vp, L);
    transpose_vp<<<dim3(32, 256), 256, 0, stream>>>(vp, vpT);

    // pass B: out[b,n,e] = P@v' - v'[n,e]*L[n]
    gemm_nt<3><<<dim3(8, 16, 4), 256, 0, stream>>>(P, vpT, out, nullptr, nullptr,
        L, nullptr, vp, 1024, 2048,
        (long)2048 * 2048, (long)1024 * 2048, (long)2048 * 1024, 2048, 0.f);
}

// Round 4
// 259.907 us; speedup vs baseline: 1.2829x; 1.1943x over previous
//
#include <hip/hip_runtime.h>
#include <hip/hip_bf16.h>
#include <cstdint>
#include <cmath>

typedef __bf16 bf16_t;
typedef __bf16 bf16x8 __attribute__((ext_vector_type(8)));
typedef __bf16 bf16x4 __attribute__((ext_vector_type(4)));
typedef float floatx4 __attribute__((ext_vector_type(4)));

#define MB ((size_t)1 << 20)

// async global->LDS, 16B per lane. LDS dest must be wave-uniform base + lane*16.
static __device__ __forceinline__ void async_load16(const void* g, void* l) {
    __builtin_amdgcn_global_load_lds(
        (const __attribute__((address_space(1))) uint32_t*)(uintptr_t)g,
        (__attribute__((address_space(3))) uint32_t*)(uint32_t)(uintptr_t)l,
        16, 0, 0);
}

// ---------------- elementwise / prep kernels ----------------
// NOTE: no atomics anywhere — all reductions use fixed summation order so the
// graph-replay output is bitwise identical to the fresh launch (bf16 rounding
// boundaries amplify 1e-7 atomic-reorder noise into 4e-5 output deltas).

__global__ void cast_x_kernel(const float* __restrict__ x, bf16_t* __restrict__ xb) {
    int i = blockIdx.x * 256 + threadIdx.x;          // one float4 per thread
    float4 v = ((const float4*)x)[i];
    bf16x4 o;
    o[0] = (bf16_t)v.x; o[1] = (bf16_t)v.y; o[2] = (bf16_t)v.z; o[3] = (bf16_t)v.w;
    ((bf16x4*)xb)[i] = o;
}

// stage 1: part[g][d] = sum_{i in [16g,16g+16)} exp(wv[i][d]), fixed row order
__global__ void colsum_stage1(const float* __restrict__ wv, float* __restrict__ part) {
    int d = blockIdx.x * 256 + threadIdx.x;    // gridDim.x = 4
    int g = blockIdx.y;                        // gridDim.y = 64
    float s = 0.f;
    #pragma unroll
    for (int i = 0; i < 16; i++) s += __expf(wv[(g * 16 + i) * 1024 + d]);
    part[g * 1024 + d] = s;
}

// stage 2: cs[d] = sum_g part[g][d], fixed g order
__global__ void colsum_stage2(const float* __restrict__ part, float* __restrict__ cs) {
    int d = blockIdx.x * 256 + threadIdx.x;    // gridDim.x = 4
    float s = 0.f;
    #pragma unroll 8
    for (int g = 0; g < 64; g++) s += part[g * 1024 + d];
    cs[d] = s;
}

// w3T[e][d] = exp(wv[e][d]) / (colsum[d]*1024)  — elementwise on wv (no transpose!)
__global__ void prep_w3(const float* __restrict__ wv, const float* __restrict__ cs,
                        bf16_t* __restrict__ w3T) {
    int idx = blockIdx.x * 256 + threadIdx.x;  // 4096 blocks
    int d = idx & 1023;
    w3T[idx] = (bf16_t)(__expf(wv[idx]) / (cs[d] * 1024.0f));
}

// WT[j][d] = W[d][j], f32 -> bf16, 32x32 LDS tile transpose; z selects {wq,wk}
__global__ void transpose_w2(const float* __restrict__ W0, const float* __restrict__ W1,
                             bf16_t* __restrict__ WT) {
    __shared__ float tile[32][33];
    const float* W = blockIdx.z ? W1 : W0;
    bf16_t* out = WT + (size_t)blockIdx.z * 1024 * 1024;
    int tx = threadIdx.x & 31, ty = threadIdx.x >> 5;   // 8 rows of 32
    int c0 = blockIdx.x * 32, r0 = blockIdx.y * 32;
    #pragma unroll
    for (int i = 0; i < 4; i++)
        tile[ty + i * 8][tx] = W[(r0 + ty + i * 8) * 1024 + c0 + tx];
    __syncthreads();
    #pragma unroll
    for (int i = 0; i < 4; i++)
        out[(long)(c0 + ty + i * 8) * 1024 + r0 + tx] = (bf16_t)tile[tx][ty + i * 8];
}

// L[z*2048+col] = sum_{y=0..15} Lpart[(z*16+y)*2048 + col], fixed y order
__global__ void reduce_L(const float* __restrict__ Lpart, float* __restrict__ L) {
    int i = blockIdx.x * 256 + threadIdx.x;    // 32 blocks -> 8192
    int z = i >> 11, col = i & 2047;
    float s = 0.f;
    #pragma unroll
    for (int y = 0; y < 16; y++) s += Lpart[(z * 16 + y) * 2048 + col];
    L[i] = s;
}

// vpT[b][e][m] = vp[b*2048+m][e] / L[b*2048+m]   (vp itself stays RAW for the -v epilogue)
__global__ void scale_transpose_vp(const bf16_t* __restrict__ vp, const float* __restrict__ L,
                                   bf16_t* __restrict__ vpT) {
    __shared__ float tile[32][33];
    int tx = threadIdx.x & 31, ty = threadIdx.x >> 5;
    int e0 = blockIdx.x * 32;   // 32
    int m0 = blockIdx.y * 32;   // 256 (global token)
    #pragma unroll
    for (int i = 0; i < 4; i++) {
        int m = m0 + ty + i * 8;
        tile[ty + i * 8][tx] = (float)vp[(long)m * 1024 + e0 + tx] * (1.0f / L[m]);
    }
    __syncthreads();
    int b = m0 >> 11, ml = m0 & 2047;
    #pragma unroll
    for (int i = 0; i < 4; i++)
        vpT[((long)(b * 1024 + e0 + ty + i * 8)) * 2048 + ml + tx] = (bf16_t)tile[tx][ty + i * 8];
}

// ---------------- NT GEMM: C[M,N] = A[M,K] * B[N,K]^T  (bf16 in, fp32 acc) ----------------
// Tile 128x128, BK=64 (32 KB LDS): 32 MFMA per barrier-pair to amortize the
// structural s_waitcnt vmcnt(0)+s_barrier drain.
// LDS swizzle: rows are 64 elems (128 B = all 32 banks); chunk c (16B) of row r
// stored at slot c ^ (r&7) -> 2-way bank aliasing only (free).
// EPI 0: store bf16, 3 output buffers selected by blockIdx.x>>3 (merged QKV)
// EPI 2: p = exp(acc*scaleExp); store bf16 P; DETERMINISTIC per-block column
//        sums -> Lpart[(z*16+blockIdx.y)*2048 + col] (no atomics)
// EPI 3: store f32: acc - Vp[row,col]   (Vp = raw v)
template <int EPI>
__global__ __launch_bounds__(256, 4) void gemm_nt(
    const bf16_t* __restrict__ A, const bf16_t* __restrict__ B, void* __restrict__ C,
    bf16_t* __restrict__ C1, bf16_t* __restrict__ C2,
    float* __restrict__ Lout, const bf16_t* __restrict__ Vp,
    int N, int K,
    long aBatch, long bBatch, long cBatch, float scaleExp)
{
    __shared__ __align__(16) bf16_t ldsA[128 * 64];
    __shared__ __align__(16) bf16_t ldsB[128 * 64];
    const int t = threadIdx.x;
    const int z = blockIdx.z;
    const bf16_t* Ab = A + (long)z * aBatch + (long)blockIdx.y * 128 * K;
    const bf16_t* Bb = B + (long)z * bBatch + (long)blockIdx.x * 128 * K;
    const int r  = t >> 3;                  // 0..31 (base row staged by this thread)
    const int cg = (t & 7) ^ (r & 7);       // swizzled global chunk for LDS slot t&7
    const bf16_t* ag0 = Ab + (long)r * K + cg * 8;
    const bf16_t* bg0 = Bb + (long)r * K + cg * 8;
    bf16_t* la = ldsA + t * 8;              // byte offset t*16 (lane-contiguous per wave)
    bf16_t* lb = ldsB + t * 8;
    const int lane = t & 63, wave = t >> 6;
    const int wm = (wave >> 1) * 64, wn = (wave & 1) * 64;
    const int fr = lane & 15;
    const int q4 = lane >> 4;               // fragment k-chunk quad
    const int sw = fr & 7;                  // read-side swizzle key

    floatx4 zero = {0.f, 0.f, 0.f, 0.f};
    floatx4 acc[4][4];
    #pragma unroll
    for (int i = 0; i < 4; i++)
        #pragma unroll
        for (int j = 0; j < 4; j++) acc[i][j] = zero;

    for (int k0 = 0; k0 < K; k0 += 64) {
        __syncthreads();
        #pragma unroll
        for (int i = 0; i < 4; i++) {
            async_load16(ag0 + (long)(32 * i) * K + k0, la + 2048 * i);
            async_load16(bg0 + (long)(32 * i) * K + k0, lb + 2048 * i);
        }
        __syncthreads();   // compiler emits s_waitcnt vmcnt(0) before barrier
        #pragma unroll
        for (int h = 0; h < 2; h++) {
            bf16x8 af[4], bfr[4];
            #pragma unroll
            for (int i = 0; i < 4; i++) {
                int row = wm + i * 16 + fr;
                af[i] = *(const bf16x8*)(ldsA + row * 64 + (((h << 2) + q4) ^ sw) * 8);
            }
            #pragma unroll
            for (int j = 0; j < 4; j++) {
                int row = wn + j * 16 + fr;
                bfr[j] = *(const bf16x8*)(ldsB + row * 64 + (((h << 2) + q4) ^ sw) * 8);
            }
            #pragma unroll
            for (int i = 0; i < 4; i++)
                #pragma unroll
                for (int j = 0; j < 4; j++)
                    acc[i][j] = __builtin_amdgcn_mfma_f32_16x16x32_bf16(af[i], bfr[j], acc[i][j], 0, 0, 0);
        }
    }

    // C/D layout: col = lane&15, row = (lane>>4)*4 + reg  [m89-verified]
    const int rq = (lane >> 4) * 4;
    const long rowBase = (long)blockIdx.y * 128 + wm;
    const int colBase = blockIdx.x * 128 + wn;

    if constexpr (EPI == 0) {
        // merged QKV: blockIdx.x in [0,24), output buffer = x>>3, col tile = x&7
        int sel = blockIdx.x >> 3;
        bf16_t* Cb = sel == 0 ? (bf16_t*)C : (sel == 1 ? C1 : C2);
        const int cB = (blockIdx.x & 7) * 128 + wn;
        #pragma unroll
        for (int mi = 0; mi < 4; mi++)
            #pragma unroll
            for (int rr = 0; rr < 4; rr++) {
                long row = rowBase + mi * 16 + rq + rr;
                #pragma unroll
                for (int ni = 0; ni < 4; ni++)
                    Cb[row * N + cB + ni * 16 + fr] = (bf16_t)acc[mi][ni][rr];
            }
    } else if constexpr (EPI == 2) {
        bf16_t* Cb = (bf16_t*)C + (long)z * cBatch;
        float csum[4] = {0.f, 0.f, 0.f, 0.f};
        #pragma unroll
        for (int mi = 0; mi < 4; mi++)
            #pragma unroll
            for (int rr = 0; rr < 4; rr++) {
                long row = rowBase + mi * 16 + rq + rr;
                #pragma unroll
                for (int ni = 0; ni < 4; ni++) {
                    float p = __expf(acc[mi][ni][rr] * scaleExp);
                    Cb[row * N + colBase + ni * 16 + fr] = (bf16_t)p;
                    csum[ni] += p;
                }
            }
        // deterministic block-level column sums -> Lpart (no atomics):
        // wave-level reduce (fixed shuffle order), stage per-half sums in LDS,
        // combine half0+half1 in fixed order, single store per column.
        float red[4];
        #pragma unroll
        for (int ni = 0; ni < 4; ni++) {
            float v = csum[ni];
            v += __shfl_xor(v, 16);
            v += __shfl_xor(v, 32);
            red[ni] = v;
        }
        __syncthreads();                      // LDS reads from K-loop fully done
        float* lf = (float*)ldsA;             // [2][128]: half (wm>>6) x column
        #pragma unroll
        for (int ni = 0; ni < 4; ni++)
            if (lane < 16)
                lf[(wm >> 6) * 128 + wn + ni * 16 + lane] = red[ni];
        __syncthreads();
        if (t < 128) {
            float s = lf[t] + lf[128 + t];
            Lout[(long)(z * 16 + blockIdx.y) * 2048 + blockIdx.x * 128 + t] = s;
        }
    } else {  // EPI == 3
        float* Co = (float*)C + (long)z * cBatch;
        const bf16_t* Vb = Vp + (long)z * cBatch;
        #pragma unroll
        for (int mi = 0; mi < 4; mi++)
            #pragma unroll
            for (int rr = 0; rr < 4; rr++) {
                long row = rowBase + mi * 16 + rq + rr;
                #pragma unroll
                for (int ni = 0; ni < 4; ni++) {
                    int col = colBase + ni * 16 + fr;
                    Co[row * N + col] = acc[mi][ni][rr] - (float)Vb[row * N + col];
                }
            }
    }
}

// ---------------- launch ----------------

extern "C" void kernel_launch(void* const* d_in, const int* in_sizes, int n_in,
                              void* d_out, int out_size, void* d_ws, size_t ws_size,
                              hipStream_t stream) {
    // setup_inputs order: x, wk, wq, wv
    const float* x  = (const float*)d_in[0];
    const float* wk = (const float*)d_in[1];
    const float* wq = (const float*)d_in[2];
    const float* wv = (const float*)d_in[3];
    float* out = (float*)d_out;

    char* ws = (char*)d_ws;
    // Workspace layout (~80.6 MB), with lifetime-based overlap:
    //   [0,16M)  xb (dead after QKV GEMM)  --> reused as start of P
    //   [16,22M) wqT|wkT|w3T contiguous (dead after QKV) --> inside P
    //   [0,32M)  P  (written in pass A, after xb/weights dead)
    //   [32,48M) wvpart (pre-QKV) -> q (dead after pass A) -> vpT
    //   [48,64M) k
    //   [64,80M) vraw (stays RAW; pass-B epilogue subtracts it)
    //   [80M,..) L (32KB) + colsum (4KB) + pad + Lpart (512KB)
    bf16_t* P      = (bf16_t*)(ws + 0);
    bf16_t* xb     = (bf16_t*)(ws + 0);
    bf16_t* wqT    = (bf16_t*)(ws + 16 * MB);   // base of the 3072x1024 concat
    bf16_t* w3T    = (bf16_t*)(ws + 20 * MB);
    bf16_t* q      = (bf16_t*)(ws + 32 * MB);
    float*  wvpart = (float*)(ws + 32 * MB);    // 256KB, dead before q written
    bf16_t* k      = (bf16_t*)(ws + 48 * MB);
    bf16_t* vp     = (bf16_t*)(ws + 64 * MB);
    bf16_t* vpT    = (bf16_t*)(ws + 32 * MB);
    float*  L      = (float*)(ws + 80 * MB);
    float*  cs     = L + 8192;
    float*  Lpart  = (float*)(ws + 80 * MB + 64 * 1024);  // 131072 floats

    const float scale = 0.022097086912079608f;  // 2048^-0.5

    cast_x_kernel<<<8192, 256, 0, stream>>>(x, xb);
    colsum_stage1<<<dim3(4, 64), 256, 0, stream>>>(wv, wvpart);
    colsum_stage2<<<4, 256, 0, stream>>>(wvpart, cs);
    prep_w3<<<4096, 256, 0, stream>>>(wv, cs, w3T);
    transpose_w2<<<dim3(32, 32, 2), 256, 0, stream>>>(wq, wk, wqT);

    // merged projections: [q|k|vraw] = x @ [wq|wk|wv_stoch]   8192 x 3072 x 1024
    gemm_nt<0><<<dim3(24, 64, 1), 256, 0, stream>>>(xb, wqT, q, k, vp,
        nullptr, nullptr, 1024, 1024, 0, 0, 0, 0.f);

    // pass A: P[b,n,m] = exp(scale * q.k), per-block column sums -> Lpart
    gemm_nt<2><<<dim3(16, 16, 4), 256, 0, stream>>>(q, k, P, nullptr, nullptr,
        Lpart, nullptr, 2048, 1024,
        (long)2048 * 1024, (long)2048 * 1024, (long)2048 * 2048, scale);

    // L = fixed-order sum of the 16 per-block partials
    reduce_L<<<32, 256, 0, stream>>>(Lpart, L);

    // vpT[b][e][m] = v/L (transposed for NT pass B); vp stays raw
    scale_transpose_vp<<<dim3(32, 256), 256, 0, stream>>>(vp, L, vpT);

    // pass B: out[b,n,e] = P@(v/L) - v[n,e]
    gemm_nt<3><<<dim3(8, 16, 4), 256, 0, stream>>>(P, vpT, out, nullptr, nullptr,
        nullptr, vp, 1024, 2048,
        (long)2048 * 2048, (long)1024 * 2048, (long)2048 * 1024, 0.f);
}

// Round 5
// 217.532 us; speedup vs baseline: 1.5328x; 1.1948x over previous
//
#include <hip/hip_runtime.h>
#include <hip/hip_bf16.h>
#include <hip/hip_fp8.h>
#include <cstdint>
#include <cmath>

typedef __bf16 bf16_t;
typedef __bf16 bf16x8 __attribute__((ext_vector_type(8)));
typedef __bf16 bf16x4 __attribute__((ext_vector_type(4)));
typedef float floatx4 __attribute__((ext_vector_type(4)));
typedef int   intx4  __attribute__((ext_vector_type(4)));
typedef int   intx8  __attribute__((ext_vector_type(8)));

#define MB ((size_t)1 << 20)

// async global->LDS, 16B per lane. LDS dest must be wave-uniform base + lane*16.
static __device__ __forceinline__ void async_load16(const void* g, void* l) {
    __builtin_amdgcn_global_load_lds(
        (const __attribute__((address_space(1))) uint32_t*)(uintptr_t)g,
        (__attribute__((address_space(3))) uint32_t*)(uint32_t)(uintptr_t)l,
        16, 0, 0);
}

// OCP e4m3 RNE saturating cast (HW cvt on gfx950 via hip_fp8.h)
static __device__ __forceinline__ uint8_t to_fp8(float v) {
    __hip_fp8_e4m3 h(v);
    return *reinterpret_cast<uint8_t*>(&h);
}

// ---------------- prep kernels (all reductions fixed-order — deterministic) --------

// merged: [0,8192) cast x->bf16 ; [8192,10240) transpose wq/wk->bf16 ;
//         [10240,10496) colsum stage1 partials
__global__ void prep_many(const float* __restrict__ x, bf16_t* __restrict__ xb,
                          const float* __restrict__ wq, const float* __restrict__ wk,
                          bf16_t* __restrict__ wT, const float* __restrict__ wv,
                          float* __restrict__ part) {
    __shared__ float tile[32][33];
    const int bid = blockIdx.x, t = threadIdx.x;
    if (bid < 8192) {
        int i = bid * 256 + t;
        float4 v = ((const float4*)x)[i];
        bf16x4 o;
        o[0] = (bf16_t)v.x; o[1] = (bf16_t)v.y; o[2] = (bf16_t)v.z; o[3] = (bf16_t)v.w;
        ((bf16x4*)xb)[i] = o;
    } else if (bid < 10240) {
        int b2 = bid - 8192;
        const float* W = (b2 >= 1024) ? wk : wq;
        bf16_t* outp = wT + (size_t)(b2 >> 10) * 1024 * 1024;
        int b3 = b2 & 1023;
        int c0 = (b3 & 31) * 32, r0 = (b3 >> 5) * 32;
        int tx = t & 31, ty = t >> 5;
        #pragma unroll
        for (int i = 0; i < 4; i++)
            tile[ty + i * 8][tx] = W[(r0 + ty + i * 8) * 1024 + c0 + tx];
        __syncthreads();
        #pragma unroll
        for (int i = 0; i < 4; i++)
            outp[(long)(c0 + ty + i * 8) * 1024 + r0 + tx] = (bf16_t)tile[tx][ty + i * 8];
    } else {
        int b = bid - 10240;            // 0..255
        int d = (b & 3) * 256 + t;
        int g = b >> 2;                 // 0..63
        float s = 0.f;
        #pragma unroll
        for (int i = 0; i < 16; i++) s += __expf(wv[(g * 16 + i) * 1024 + d]);
        part[g * 1024 + d] = s;
    }
}

// cs[d] = sum_g part[g][d], fixed g order
__global__ void colsum_stage2(const float* __restrict__ part, float* __restrict__ cs) {
    int d = blockIdx.x * 256 + threadIdx.x;    // gridDim.x = 4
    float s = 0.f;
    #pragma unroll 8
    for (int g = 0; g < 64; g++) s += part[g * 1024 + d];
    cs[d] = s;
}

// w3T[e][d] = exp(wv[e][d]) / (colsum[d]*1024)  — elementwise on wv
__global__ void prep_w3(const float* __restrict__ wv, const float* __restrict__ cs,
                        bf16_t* __restrict__ w3T) {
    int idx = blockIdx.x * 256 + threadIdx.x;  // 4096 blocks
    int d = idx & 1023;
    w3T[idx] = (bf16_t)(__expf(wv[idx]) / (cs[d] * 1024.0f));
}

// vpT[b][e][m] = fp8( vp[b*2048+m][e] * 2^30 / L[b*2048+m] ), L reduced here from
// Lpart in fixed order (identical redundant compute per e-block — deterministic).
// vp itself stays RAW bf16 for pass-B's "- v" epilogue.
__global__ void scale_transpose_vp(const bf16_t* __restrict__ vp,
                                   const float* __restrict__ Lpart,
                                   uint8_t* __restrict__ vpT) {
    __shared__ float tile[32][33];
    __shared__ float ls[32];
    int t = threadIdx.x;
    int tx = t & 31, ty = t >> 5;
    int e0 = blockIdx.x * 32;   // 32
    int m0 = blockIdx.y * 32;   // 256 (global token)
    if (t < 32) {
        int m = m0 + t, z = m >> 11, ml = m & 2047;
        float s = 0.f;
        #pragma unroll
        for (int y = 0; y < 16; y++) s += Lpart[(z * 16 + y) * 2048 + ml];
        ls[t] = 1073741824.0f / s;      // 2^30 / L  (2^30 exact, undone in pass B)
    }
    __syncthreads();
    #pragma unroll
    for (int i = 0; i < 4; i++) {
        int mr = ty + i * 8;
        tile[mr][tx] = (float)vp[(long)(m0 + mr) * 1024 + e0 + tx] * ls[mr];
    }
    __syncthreads();
    int b = m0 >> 11, ml = m0 & 2047;
    #pragma unroll
    for (int i = 0; i < 4; i++)
        vpT[((long)(b * 1024 + e0 + ty + i * 8)) * 2048 + ml + tx] = to_fp8(tile[tx][ty + i * 8]);
}

// ---------------- QKV GEMM (bf16): [q8|k8|vp] = xb @ wcat^T ----------------
// Tile 128x128, BK=64, swizzled LDS (r4-verified). q,k outputs cast to fp8 e4m3
// (attention-path precision is sufficient); v output stays bf16 (feeds -v term).
__global__ __launch_bounds__(256, 4) void gemm_qkv(
    const bf16_t* __restrict__ A, const bf16_t* __restrict__ B,
    uint8_t* __restrict__ Cq, uint8_t* __restrict__ Ck, bf16_t* __restrict__ Cv)
{
    const int K = 1024;
    __shared__ __align__(16) bf16_t ldsA[128 * 64];
    __shared__ __align__(16) bf16_t ldsB[128 * 64];
    const int t = threadIdx.x;
    const bf16_t* Ab = A + (long)blockIdx.y * 128 * K;
    const bf16_t* Bb = B + (long)blockIdx.x * 128 * K;
    const int r  = t >> 3;
    const int cg = (t & 7) ^ (r & 7);
    const bf16_t* ag0 = Ab + (long)r * K + cg * 8;
    const bf16_t* bg0 = Bb + (long)r * K + cg * 8;
    bf16_t* la = ldsA + t * 8;
    bf16_t* lb = ldsB + t * 8;
    const int lane = t & 63, wave = t >> 6;
    const int wm = (wave >> 1) * 64, wn = (wave & 1) * 64;
    const int fr = lane & 15;
    const int q4 = lane >> 4;
    const int sw = fr & 7;

    floatx4 zero = {0.f, 0.f, 0.f, 0.f};
    floatx4 acc[4][4];
    #pragma unroll
    for (int i = 0; i < 4; i++)
        #pragma unroll
        for (int j = 0; j < 4; j++) acc[i][j] = zero;

    for (int k0 = 0; k0 < K; k0 += 64) {
        __syncthreads();
        #pragma unroll
        for (int i = 0; i < 4; i++) {
            async_load16(ag0 + (long)(32 * i) * K + k0, la + 2048 * i);
            async_load16(bg0 + (long)(32 * i) * K + k0, lb + 2048 * i);
        }
        __syncthreads();
        #pragma unroll
        for (int h = 0; h < 2; h++) {
            bf16x8 af[4], bfr[4];
            #pragma unroll
            for (int i = 0; i < 4; i++) {
                int row = wm + i * 16 + fr;
                af[i] = *(const bf16x8*)(ldsA + row * 64 + (((h << 2) + q4) ^ sw) * 8);
            }
            #pragma unroll
            for (int j = 0; j < 4; j++) {
                int row = wn + j * 16 + fr;
                bfr[j] = *(const bf16x8*)(ldsB + row * 64 + (((h << 2) + q4) ^ sw) * 8);
            }
            #pragma unroll
            for (int i = 0; i < 4; i++)
                #pragma unroll
                for (int j = 0; j < 4; j++)
                    acc[i][j] = __builtin_amdgcn_mfma_f32_16x16x32_bf16(af[i], bfr[j], acc[i][j], 0, 0, 0);
        }
    }

    const int rq = (lane >> 4) * 4;
    const long rowBase = (long)blockIdx.y * 128 + wm;
    const int sel = blockIdx.x >> 3;                  // 0=q, 1=k, 2=v
    const int cB = (blockIdx.x & 7) * 128 + wn;

    if (sel == 2) {
        #pragma unroll
        for (int mi = 0; mi < 4; mi++)
            #pragma unroll
            for (int rr = 0; rr < 4; rr++) {
                long row = rowBase + mi * 16 + rq + rr;
                #pragma unroll
                for (int ni = 0; ni < 4; ni++)
                    Cv[row * 1024 + cB + ni * 16 + fr] = (bf16_t)acc[mi][ni][rr];
            }
    } else {
        uint8_t* Cb = sel ? Ck : Cq;
        #pragma unroll
        for (int mi = 0; mi < 4; mi++)
            #pragma unroll
            for (int rr = 0; rr < 4; rr++) {
                long row = rowBase + mi * 16 + rq + rr;
                #pragma unroll
                for (int ni = 0; ni < 4; ni++)
                    Cb[row * 1024 + cB + ni * 16 + fr] = to_fp8(acc[mi][ni][rr]);
            }
    }
}

// ---------------- MX-fp8 NT GEMM: C = A[M,K] * B[N,K]^T, K-step 128 ----------------
// A,B fp8 e4m3, unit scales (0x7f = 2^0). Tile 128x128, 128 B/row LDS with the
// same c^(r&7) chunk swizzle (2-way bank aliasing, free). Fragment: 32 bytes/lane,
// A[m=lane&15][k=(lane>>4)*32 + j] — K-extension of the verified bf16 layout.
// EPI 2: p = exp(acc*scaleExp); store fp8 P; deterministic per-block column sums
//        -> Lpart[(z*16+blockIdx.y)*2048 + col] (no atomics)
// EPI 3: store f32: acc*2^-30 - Vp[row,col]   (Vp = raw bf16 v)
template <int EPI>
__global__ __launch_bounds__(256, 3) void gemm_nt_fp8(
    const uint8_t* __restrict__ A, const uint8_t* __restrict__ B, void* __restrict__ C,
    float* __restrict__ Lout, const bf16_t* __restrict__ Vp,
    int N, int K, long aBatch, long bBatch, long cBatch, float scaleExp)
{
    __shared__ __align__(16) uint8_t ldsA[128 * 128];
    __shared__ __align__(16) uint8_t ldsB[128 * 128];
    const int t = threadIdx.x;
    const int z = blockIdx.z;
    const uint8_t* Ab = A + (long)z * aBatch + (long)blockIdx.y * 128 * K;
    const uint8_t* Bb = B + (long)z * bBatch + (long)blockIdx.x * 128 * K;
    const int r  = t >> 3;                  // 0..31 (row within 32-row staging group)
    const int cg = (t & 7) ^ (r & 7);       // global chunk for LDS slot t&7
    const uint8_t* ag0 = Ab + (long)r * K + cg * 16;
    const uint8_t* bg0 = Bb + (long)r * K + cg * 16;
    uint8_t* la = ldsA + t * 16;
    uint8_t* lb = ldsB + t * 16;
    const int lane = t & 63, wave = t >> 6;
    const int wm = (wave >> 1) * 64, wn = (wave & 1) * 64;
    const int fr = lane & 15;
    const int q4 = lane >> 4;               // k-group: k in [32*q4, 32*q4+32)
    const int sw = fr & 7;

    floatx4 zero = {0.f, 0.f, 0.f, 0.f};
    floatx4 acc[4][4];
    #pragma unroll
    for (int i = 0; i < 4; i++)
        #pragma unroll
        for (int j = 0; j < 4; j++) acc[i][j] = zero;

    for (int k0 = 0; k0 < K; k0 += 128) {
        __syncthreads();
        #pragma unroll
        for (int i = 0; i < 4; i++) {
            async_load16(ag0 + (long)(32 * i) * K + k0, la + 4096 * i);
            async_load16(bg0 + (long)(32 * i) * K + k0, lb + 4096 * i);
        }
        __syncthreads();
        intx8 af[4], bfr[4];
        #pragma unroll
        for (int i = 0; i < 4; i++) {
            int row = wm + i * 16 + fr;
            intx4 lo = *(const intx4*)(ldsA + row * 128 + ((2 * q4) ^ sw) * 16);
            intx4 hi = *(const intx4*)(ldsA + row * 128 + ((2 * q4 + 1) ^ sw) * 16);
            af[i][0] = lo[0]; af[i][1] = lo[1]; af[i][2] = lo[2]; af[i][3] = lo[3];
            af[i][4] = hi[0]; af[i][5] = hi[1]; af[i][6] = hi[2]; af[i][7] = hi[3];
        }
        #pragma unroll
        for (int j = 0; j < 4; j++) {
            int row = wn + j * 16 + fr;
            intx4 lo = *(const intx4*)(ldsB + row * 128 + ((2 * q4) ^ sw) * 16);
            intx4 hi = *(const intx4*)(ldsB + row * 128 + ((2 * q4 + 1) ^ sw) * 16);
            bfr[j][0] = lo[0]; bfr[j][1] = lo[1]; bfr[j][2] = lo[2]; bfr[j][3] = lo[3];
            bfr[j][4] = hi[0]; bfr[j][5] = hi[1]; bfr[j][6] = hi[2]; bfr[j][7] = hi[3];
        }
        #pragma unroll
        for (int i = 0; i < 4; i++)
            #pragma unroll
            for (int j = 0; j < 4; j++)
                acc[i][j] = __builtin_amdgcn_mfma_scale_f32_16x16x128_f8f6f4(
                    af[i], bfr[j], acc[i][j], 0, 0,      // cbsz=fp8, blgp=fp8
                    0, 0x7f7f7f7f, 0, 0x7f7f7f7f);       // unit scales (e8m0 bias 127)
    }

    // C/D layout: col = lane&15, row = (lane>>4)*4 + reg (shape-determined, dtype-indep)
    const int rq = (lane >> 4) * 4;
    const long rowBase = (long)blockIdx.y * 128 + wm;
    const int colBase = blockIdx.x * 128 + wn;

    if constexpr (EPI == 2) {
        uint8_t* Cb = (uint8_t*)C + (long)z * cBatch;
        float csum[4] = {0.f, 0.f, 0.f, 0.f};
        #pragma unroll
        for (int mi = 0; mi < 4; mi++)
            #pragma unroll
            for (int rr = 0; rr < 4; rr++) {
                long row = rowBase + mi * 16 + rq + rr;
                #pragma unroll
                for (int ni = 0; ni < 4; ni++) {
                    float p = __expf(acc[mi][ni][rr] * scaleExp);
                    Cb[row * N + colBase + ni * 16 + fr] = to_fp8(p);
                    csum[ni] += p;
                }
            }
        float red[4];
        #pragma unroll
        for (int ni = 0; ni < 4; ni++) {
            float v = csum[ni];
            v += __shfl_xor(v, 16);
            v += __shfl_xor(v, 32);
            red[ni] = v;
        }
        __syncthreads();
        float* lf = (float*)ldsA;             // [2][128]: half (wm>>6) x column
        #pragma unroll
        for (int ni = 0; ni < 4; ni++)
            if (lane < 16)
                lf[(wm >> 6) * 128 + wn + ni * 16 + lane] = red[ni];
        __syncthreads();
        if (t < 128) {
            float s = lf[t] + lf[128 + t];
            Lout[(long)(z * 16 + blockIdx.y) * 2048 + blockIdx.x * 128 + t] = s;
        }
    } else {  // EPI == 3
        float* Co = (float*)C + (long)z * cBatch;
        const bf16_t* Vb = Vp + (long)z * cBatch;
        const float inv230 = 9.313225746154785e-10f;   // 2^-30 exact
        #pragma unroll
        for (int mi = 0; mi < 4; mi++)
            #pragma unroll
            for (int rr = 0; rr < 4; rr++) {
                long row = rowBase + mi * 16 + rq + rr;
                #pragma unroll
                for (int ni = 0; ni < 4; ni++) {
                    int col = colBase + ni * 16 + fr;
                    Co[row * N + col] = acc[mi][ni][rr] * inv230 - (float)Vb[row * N + col];
                }
            }
    }
}

// ---------------- launch ----------------

extern "C" void kernel_launch(void* const* d_in, const int* in_sizes, int n_in,
                              void* d_out, int out_size, void* d_ws, size_t ws_size,
                              hipStream_t stream) {
    // setup_inputs order: x, wk, wq, wv
    const float* x  = (const float*)d_in[0];
    const float* wk = (const float*)d_in[1];
    const float* wq = (const float*)d_in[2];
    const float* wv = (const float*)d_in[3];
    float* out = (float*)d_out;

    char* ws = (char*)d_ws;
    // Workspace (~80.6 MB), lifetime-overlapped:
    //   [0,16M)   xb bf16 (dead after QKV) -> P fp8 (16 MB, written in pass A)
    //   [16,22M)  wqT|wkT|w3T bf16 concat (dead after QKV)
    //   [32,33M)  wvpart (dead after colsum2) -> [32,40M) q8 fp8 (dead after A) -> vpT fp8
    //   [48,56M)  k8 fp8
    //   [64,80M)  vp bf16 (raw v; pass-B epilogue subtracts it)
    //   [80M)     cs (4KB); [80M+64K) Lpart (512KB)
    bf16_t*  P_dummy = nullptr; (void)P_dummy;
    uint8_t* P      = (uint8_t*)(ws + 0);
    bf16_t*  xb     = (bf16_t*)(ws + 0);
    bf16_t*  wqT    = (bf16_t*)(ws + 16 * MB);   // base of 3072x1024 concat
    bf16_t*  w3T    = (bf16_t*)(ws + 20 * MB);
    float*   wvpart = (float*)(ws + 32 * MB);
    uint8_t* q8     = (uint8_t*)(ws + 32 * MB);
    uint8_t* vpT    = (uint8_t*)(ws + 32 * MB);
    uint8_t* k8     = (uint8_t*)(ws + 48 * MB);
    bf16_t*  vp     = (bf16_t*)(ws + 64 * MB);
    float*   cs     = (float*)(ws + 80 * MB);
    float*   Lpart  = (float*)(ws + 80 * MB + 64 * 1024);  // 131072 floats

    const float scale = 0.022097086912079608f;  // 2048^-0.5

    // prep: cast x, transpose wq/wk, colsum partials — one fused dispatch
    prep_many<<<10496, 256, 0, stream>>>(x, xb, wq, wk, wqT, wv, wvpart);
    colsum_stage2<<<4, 256, 0, stream>>>(wvpart, cs);
    prep_w3<<<4096, 256, 0, stream>>>(wv, cs, w3T);

    // merged projections: q8/k8 (fp8) + vraw (bf16) = x @ [wq|wk|wv_stoch]
    gemm_qkv<<<dim3(24, 64, 1), 256, 0, stream>>>(xb, wqT, q8, k8, vp);

    // pass A (MX-fp8): P[b,n,m] = fp8(exp(scale * q.k)), col sums -> Lpart
    gemm_nt_fp8<2><<<dim3(16, 16, 4), 256, 0, stream>>>(q8, k8, P,
        Lpart, nullptr, 2048, 1024,
        (long)2048 * 1024, (long)2048 * 1024, (long)2048 * 2048, scale);

    // vpT = fp8(v * 2^30 / L) transposed; L reduced in-kernel (fixed order)
    scale_transpose_vp<<<dim3(32, 256), 256, 0, stream>>>(vp, Lpart, vpT);

    // pass B (MX-fp8): out[b,n,e] = (P @ vpT^T)*2^-30 - v[n,e]
    gemm_nt_fp8<3><<<dim3(8, 16, 4), 256, 0, stream>>>(P, vpT, out,
        nullptr, vp, 1024, 2048,
        (long)2048 * 2048, (long)1024 * 2048, (long)2048 * 1024, 0.f);
}

// Round 6
// 189.678 us; speedup vs baseline: 1.7579x; 1.1468x over previous
//
#include <hip/hip_runtime.h>
#include <hip/hip_bf16.h>
#include <hip/hip_fp8.h>
#include <cstdint>
#include <cmath>

typedef __bf16 bf16_t;
typedef __bf16 bf16x8 __attribute__((ext_vector_type(8)));
typedef __bf16 bf16x4 __attribute__((ext_vector_type(4)));
typedef float floatx4 __attribute__((ext_vector_type(4)));
typedef int   intx4  __attribute__((ext_vector_type(4)));
typedef int   intx8  __attribute__((ext_vector_type(8)));

#define MB ((size_t)1 << 20)

// async global->LDS, 16B per lane. LDS dest must be wave-uniform base + lane*16.
static __device__ __forceinline__ void async_load16(const void* g, void* l) {
    __builtin_amdgcn_global_load_lds(
        (const __attribute__((address_space(1))) uint32_t*)(uintptr_t)g,
        (__attribute__((address_space(3))) uint32_t*)(uint32_t)(uintptr_t)l,
        16, 0, 0);
}

// OCP e4m3 RNE saturating cast (HW cvt on gfx950 via hip_fp8.h)
static __device__ __forceinline__ uint8_t to_fp8(float v) {
    __hip_fp8_e4m3 h(v);
    return *reinterpret_cast<uint8_t*>(&h);
}

// ---------------- prep kernels (all reductions fixed-order — deterministic) --------

// merged: [0,8192)      cast x->fp8 (one row/block) + exact fp32 row sums S[n]
//         [8192,10240)  transpose wq/wk -> fp8 into wcat8 rows [0,2048)
//         [10240,10496) colsum stage1 partials
__global__ void prep_many(const float* __restrict__ x, uint8_t* __restrict__ x8,
                          float* __restrict__ Srow,
                          const float* __restrict__ wq, const float* __restrict__ wk,
                          uint8_t* __restrict__ wcat8, const float* __restrict__ wv,
                          float* __restrict__ part) {
    __shared__ float tile[32][33];
    __shared__ float wsum[4];
    const int bid = blockIdx.x, t = threadIdx.x;
    if (bid < 8192) {
        // one token row: cast 1024 floats -> fp8, and S[row] = exact fixed-order sum
        int i = bid * 256 + t;
        float4 v = ((const float4*)x)[i];
        uint32_t pk = (uint32_t)to_fp8(v.x) | ((uint32_t)to_fp8(v.y) << 8) |
                      ((uint32_t)to_fp8(v.z) << 16) | ((uint32_t)to_fp8(v.w) << 24);
        ((uint32_t*)x8)[i] = pk;
        float s = (v.x + v.y) + (v.z + v.w);
        #pragma unroll
        for (int d = 1; d < 64; d <<= 1) s += __shfl_xor(s, d);
        if ((t & 63) == 0) wsum[t >> 6] = s;
        __syncthreads();
        if (t == 0) Srow[bid] = (wsum[0] + wsum[1]) + (wsum[2] + wsum[3]);
    } else if (bid < 10240) {
        int b2 = bid - 8192;
        const float* W = (b2 >= 1024) ? wk : wq;
        uint8_t* outp = wcat8 + (size_t)(b2 >> 10) * 1024 * 1024;
        int b3 = b2 & 1023;
        int c0 = (b3 & 31) * 32, r0 = (b3 >> 5) * 32;
        int tx = t & 31, ty = t >> 5;
        #pragma unroll
        for (int i = 0; i < 4; i++)
            tile[ty + i * 8][tx] = W[(r0 + ty + i * 8) * 1024 + c0 + tx];
        __syncthreads();
        #pragma unroll
        for (int i = 0; i < 4; i++)
            outp[(long)(c0 + ty + i * 8) * 1024 + r0 + tx] = to_fp8(tile[tx][ty + i * 8]);
    } else {
        int b = bid - 10240;            // 0..255
        int d = (b & 3) * 256 + t;
        int g = b >> 2;                 // 0..63
        float s = 0.f;
        #pragma unroll
        for (int i = 0; i < 16; i++) s += __expf(wv[(g * 16 + i) * 1024 + d]);
        part[g * 1024 + d] = s;
    }
}

// cs[d] = sum_g part[g][d], fixed g order
__global__ void colsum_stage2(const float* __restrict__ part, float* __restrict__ cs) {
    int d = blockIdx.x * 256 + threadIdx.x;    // gridDim.x = 4
    float s = 0.f;
    #pragma unroll 8
    for (int g = 0; g < 64; g++) s += part[g * 1024 + d];
    cs[d] = s;
}

// delta8[e][d] = fp8( 16 * (1024*exp(wv[e,d])/cs[d] - 1) )  — the deviation of
// 2^20*wv_stoch from its rank-1 mean, scaled x16 into fp8 normal range.
__global__ void prep_delta(const float* __restrict__ wv, const float* __restrict__ cs,
                           uint8_t* __restrict__ delta8) {
    int idx = blockIdx.x * 256 + threadIdx.x;  // 4096 blocks
    int d = idx & 1023;
    float r = __expf(wv[idx]) * 1024.0f / cs[d] - 1.0f;
    delta8[idx] = to_fp8(r * 16.0f);
}

// vpT[b][e][m] = fp8( vp[b*2048+m][e] * 2^30 / L[b*2048+m] ), L reduced here from
// Lpart in fixed order. vp itself stays RAW bf16 for pass-B's "- v" epilogue.
__global__ void scale_transpose_vp(const bf16_t* __restrict__ vp,
                                   const float* __restrict__ Lpart,
                                   uint8_t* __restrict__ vpT) {
    __shared__ float tile[32][33];
    __shared__ float ls[32];
    int t = threadIdx.x;
    int tx = t & 31, ty = t >> 5;
    int e0 = blockIdx.x * 32;   // 32
    int m0 = blockIdx.y * 32;   // 256 (global token)
    if (t < 32) {
        int m = m0 + t, z = m >> 11, ml = m & 2047;
        float s = 0.f;
        #pragma unroll
        for (int y = 0; y < 16; y++) s += Lpart[(z * 16 + y) * 2048 + ml];
        ls[t] = 1073741824.0f / s;      // 2^30 / L  (2^30 exact, undone in pass B)
    }
    __syncthreads();
    #pragma unroll
    for (int i = 0; i < 4; i++) {
        int mr = ty + i * 8;
        tile[mr][tx] = (float)vp[(long)(m0 + mr) * 1024 + e0 + tx] * ls[mr];
    }
    __syncthreads();
    int b = m0 >> 11, ml = m0 & 2047;
    #pragma unroll
    for (int i = 0; i < 4; i++)
        vpT[((long)(b * 1024 + e0 + ty + i * 8)) * 2048 + ml + tx] = to_fp8(tile[tx][ty + i * 8]);
}

// ---------------- MX-fp8 NT GEMM: C = A[M,K] * B[N,K]^T, K-step 128 ----------------
// A,B fp8 e4m3, unit scales (0x7f = 2^0). Tile 128x128, 128 B/row LDS with the
// c^(r&7) chunk swizzle (2-way bank aliasing, free). Fragment: 32 bytes/lane,
// A[m=lane&15][k=(lane>>4)*32 + j] — r5-verified end-to-end.
// EPI 0: merged QKV: blockIdx.x>>3 selects {q8 fp8, k8 fp8, v bf16}. v epilogue
//        applies the rank-1 reconstruction: v = acc*2^-24 + S[row]*2^-20.
// EPI 2: p = exp(acc*scaleExp); store fp8 P; deterministic per-block column sums
//        -> Lpart[(z*16+blockIdx.y)*2048 + col] (no atomics)
// EPI 3: store f32: acc*2^-30 - Vp[row,col]   (Vp = raw bf16 v)
template <int EPI>
__global__ __launch_bounds__(256, 3) void gemm_nt_fp8(
    const uint8_t* __restrict__ A, const uint8_t* __restrict__ B, void* __restrict__ C,
    uint8_t* __restrict__ C1, bf16_t* __restrict__ Cv, const float* __restrict__ Srow,
    float* __restrict__ Lout, const bf16_t* __restrict__ Vp,
    int N, int K, long aBatch, long bBatch, long cBatch, float scaleExp)
{
    __shared__ __align__(16) uint8_t ldsA[128 * 128];
    __shared__ __align__(16) uint8_t ldsB[128 * 128];
    const int t = threadIdx.x;
    const int z = blockIdx.z;
    const uint8_t* Ab = A + (long)z * aBatch + (long)blockIdx.y * 128 * K;
    const uint8_t* Bb = B + (long)z * bBatch + (long)blockIdx.x * 128 * K;
    const int r  = t >> 3;                  // 0..31 (row within 32-row staging group)
    const int cg = (t & 7) ^ (r & 7);       // global chunk for LDS slot t&7
    const uint8_t* ag0 = Ab + (long)r * K + cg * 16;
    const uint8_t* bg0 = Bb + (long)r * K + cg * 16;
    uint8_t* la = ldsA + t * 16;
    uint8_t* lb = ldsB + t * 16;
    const int lane = t & 63, wave = t >> 6;
    const int wm = (wave >> 1) * 64, wn = (wave & 1) * 64;
    const int fr = lane & 15;
    const int q4 = lane >> 4;               // k-group: k in [32*q4, 32*q4+32)
    const int sw = fr & 7;

    floatx4 zero = {0.f, 0.f, 0.f, 0.f};
    floatx4 acc[4][4];
    #pragma unroll
    for (int i = 0; i < 4; i++)
        #pragma unroll
        for (int j = 0; j < 4; j++) acc[i][j] = zero;

    for (int k0 = 0; k0 < K; k0 += 128) {
        __syncthreads();
        #pragma unroll
        for (int i = 0; i < 4; i++) {
            async_load16(ag0 + (long)(32 * i) * K + k0, la + 4096 * i);
            async_load16(bg0 + (long)(32 * i) * K + k0, lb + 4096 * i);
        }
        __syncthreads();
        intx8 af[4], bfr[4];
        #pragma unroll
        for (int i = 0; i < 4; i++) {
            int row = wm + i * 16 + fr;
            intx4 lo = *(const intx4*)(ldsA + row * 128 + ((2 * q4) ^ sw) * 16);
            intx4 hi = *(const intx4*)(ldsA + row * 128 + ((2 * q4 + 1) ^ sw) * 16);
            af[i][0] = lo[0]; af[i][1] = lo[1]; af[i][2] = lo[2]; af[i][3] = lo[3];
            af[i][4] = hi[0]; af[i][5] = hi[1]; af[i][6] = hi[2]; af[i][7] = hi[3];
        }
        #pragma unroll
        for (int j = 0; j < 4; j++) {
            int row = wn + j * 16 + fr;
            intx4 lo = *(const intx4*)(ldsB + row * 128 + ((2 * q4) ^ sw) * 16);
            intx4 hi = *(const intx4*)(ldsB + row * 128 + ((2 * q4 + 1) ^ sw) * 16);
            bfr[j][0] = lo[0]; bfr[j][1] = lo[1]; bfr[j][2] = lo[2]; bfr[j][3] = lo[3];
            bfr[j][4] = hi[0]; bfr[j][5] = hi[1]; bfr[j][6] = hi[2]; bfr[j][7] = hi[3];
        }
        #pragma unroll
        for (int i = 0; i < 4; i++)
            #pragma unroll
            for (int j = 0; j < 4; j++)
                acc[i][j] = __builtin_amdgcn_mfma_scale_f32_16x16x128_f8f6f4(
                    af[i], bfr[j], acc[i][j], 0, 0,      // cbsz=fp8, blgp=fp8
                    0, 0x7f7f7f7f, 0, 0x7f7f7f7f);       // unit scales (e8m0 bias 127)
    }

    // C/D layout: col = lane&15, row = (lane>>4)*4 + reg (shape-determined, dtype-indep)
    const int rq = (lane >> 4) * 4;
    const long rowBase = (long)blockIdx.y * 128 + wm;
    const int colBase = blockIdx.x * 128 + wn;

    if constexpr (EPI == 0) {
        const int sel = blockIdx.x >> 3;              // 0=q8, 1=k8, 2=v(bf16)
        const int cB = (blockIdx.x & 7) * 128 + wn;
        if (sel == 2) {
            const float c24 = 5.9604644775390625e-08f;   // 2^-24 (acc holds 16*sum(x*delta))
            const float c20 = 9.5367431640625e-07f;      // 2^-20
            #pragma unroll
            for (int mi = 0; mi < 4; mi++)
                #pragma unroll
                for (int rr = 0; rr < 4; rr++) {
                    long row = rowBase + mi * 16 + rq + rr;
                    float sv = Srow[row] * c20;
                    #pragma unroll
                    for (int ni = 0; ni < 4; ni++)
                        Cv[row * 1024 + cB + ni * 16 + fr] =
                            (bf16_t)(acc[mi][ni][rr] * c24 + sv);
                }
        } else {
            uint8_t* Cb = sel ? C1 : (uint8_t*)C;
            #pragma unroll
            for (int mi = 0; mi < 4; mi++)
                #pragma unroll
                for (int rr = 0; rr < 4; rr++) {
                    long row = rowBase + mi * 16 + rq + rr;
                    #pragma unroll
                    for (int ni = 0; ni < 4; ni++)
                        Cb[row * 1024 + cB + ni * 16 + fr] = to_fp8(acc[mi][ni][rr]);
                }
        }
    } else if constexpr (EPI == 2) {
        uint8_t* Cb = (uint8_t*)C + (long)z * cBatch;
        float csum[4] = {0.f, 0.f, 0.f, 0.f};
        #pragma unroll
        for (int mi = 0; mi < 4; mi++)
            #pragma unroll
            for (int rr = 0; rr < 4; rr++) {
                long row = rowBase + mi * 16 + rq + rr;
                #pragma unroll
                for (int ni = 0; ni < 4; ni++) {
                    float p = __expf(acc[mi][ni][rr] * scaleExp);
                    Cb[row * N + colBase + ni * 16 + fr] = to_fp8(p);
                    csum[ni] += p;
                }
            }
        float red[4];
        #pragma unroll
        for (int ni = 0; ni < 4; ni++) {
            float v = csum[ni];
            v += __shfl_xor(v, 16);
            v += __shfl_xor(v, 32);
            red[ni] = v;
        }
        __syncthreads();
        float* lf = (float*)ldsA;             // [2][128]: half (wm>>6) x column
        #pragma unroll
        for (int ni = 0; ni < 4; ni++)
            if (lane < 16)
                lf[(wm >> 6) * 128 + wn + ni * 16 + lane] = red[ni];
        __syncthreads();
        if (t < 128) {
            float s = lf[t] + lf[128 + t];
            Lout[(long)(z * 16 + blockIdx.y) * 2048 + blockIdx.x * 128 + t] = s;
        }
    } else {  // EPI == 3
        float* Co = (float*)C + (long)z * cBatch;
        const bf16_t* Vb = Vp + (long)z * cBatch;
        const float inv230 = 9.313225746154785e-10f;   // 2^-30 exact
        #pragma unroll
        for (int mi = 0; mi < 4; mi++)
            #pragma unroll
            for (int rr = 0; rr < 4; rr++) {
                long row = rowBase + mi * 16 + rq + rr;
                #pragma unroll
                for (int ni = 0; ni < 4; ni++) {
                    int col = colBase + ni * 16 + fr;
                    Co[row * N + col] = acc[mi][ni][rr] * inv230 - (float)Vb[row * N + col];
                }
            }
    }
}

// ---------------- launch ----------------

extern "C" void kernel_launch(void* const* d_in, const int* in_sizes, int n_in,
                              void* d_out, int out_size, void* d_ws, size_t ws_size,
                              hipStream_t stream) {
    // setup_inputs order: x, wk, wq, wv
    const float* x  = (const float*)d_in[0];
    const float* wk = (const float*)d_in[1];
    const float* wq = (const float*)d_in[2];
    const float* wv = (const float*)d_in[3];
    float* out = (float*)d_out;

    char* ws = (char*)d_ws;
    // Workspace (~80.6 MB), lifetime-overlapped:
    //   [0,8M)    x8 fp8 (dead after QKV) \
    //   [8,11M)   wcat8 = [wq8T|wk8T|16*delta8] (dead after QKV) -> P fp8 [0,16M)
    //   [32,33M)  wvpart (dead after colsum2) -> [32,40M) q8 (dead after A) -> vpT
    //   [48,56M)  k8 fp8
    //   [64,80M)  vp bf16 (raw v; pass-B epilogue subtracts it)
    //   [80M) cs (4KB); [80M+16K) Srow (32KB); [80M+64K) Lpart (512KB)
    uint8_t* x8     = (uint8_t*)(ws + 0);
    uint8_t* wcat8  = (uint8_t*)(ws + 8 * MB);
    uint8_t* delta8 = wcat8 + 2u * 1024 * 1024;
    uint8_t* P      = (uint8_t*)(ws + 0);
    float*   wvpart = (float*)(ws + 32 * MB);
    uint8_t* q8     = (uint8_t*)(ws + 32 * MB);
    uint8_t* vpT    = (uint8_t*)(ws + 32 * MB);
    uint8_t* k8     = (uint8_t*)(ws + 48 * MB);
    bf16_t*  vp     = (bf16_t*)(ws + 64 * MB);
    float*   cs     = (float*)(ws + 80 * MB);
    float*   Srow   = (float*)(ws + 80 * MB + 16 * 1024);
    float*   Lpart  = (float*)(ws + 80 * MB + 64 * 1024);  // 131072 floats

    const float scale = 0.022097086912079608f;  // 2048^-0.5

    // prep: cast x->fp8 + row sums S, transpose wq/wk->fp8, colsum partials
    prep_many<<<10496, 256, 0, stream>>>(x, x8, Srow, wq, wk, wcat8, wv, wvpart);
    colsum_stage2<<<4, 256, 0, stream>>>(wvpart, cs);
    prep_delta<<<4096, 256, 0, stream>>>(wv, cs, delta8);

    // merged QKV (MX-fp8): [q8|k8|16*sum(x*delta)] = x8 @ wcat8^T
    // v reconstructed in epilogue: v = acc*2^-24 + S[row]*2^-20  (bf16)
    gemm_nt_fp8<0><<<dim3(24, 64, 1), 256, 0, stream>>>(x8, wcat8, q8,
        k8, vp, Srow, nullptr, nullptr, 1024, 1024, 0, 0, 0, 0.f);

    // pass A (MX-fp8): P[b,n,m] = fp8(exp(scale * q.k)), col sums -> Lpart
    gemm_nt_fp8<2><<<dim3(16, 16, 4), 256, 0, stream>>>(q8, k8, P,
        nullptr, nullptr, nullptr, Lpart, nullptr, 2048, 1024,
        (long)2048 * 1024, (long)2048 * 1024, (long)2048 * 2048, scale);

    // vpT = fp8(v * 2^30 / L) transposed; L reduced in-kernel (fixed order)
    scale_transpose_vp<<<dim3(32, 256), 256, 0, stream>>>(vp, Lpart, vpT);

    // pass B (MX-fp8): out[b,n,e] = (P @ vpT^T)*2^-30 - v[n,e]
    gemm_nt_fp8<3><<<dim3(8, 16, 4), 256, 0, stream>>>(P, vpT, out,
        nullptr, nullptr, nullptr, nullptr, vp, 1024, 2048,
        (long)2048 * 2048, (long)1024 * 2048, (long)2048 * 1024, 0.f);
}

// Round 7
// 186.980 us; speedup vs baseline: 1.7833x; 1.0144x over previous
//
#include <hip/hip_runtime.h>
#include <hip/hip_bf16.h>
#include <hip/hip_fp8.h>
#include <cstdint>
#include <cmath>

typedef __bf16 bf16_t;
typedef __bf16 bf16x8 __attribute__((ext_vector_type(8)));
typedef __bf16 bf16x4 __attribute__((ext_vector_type(4)));
typedef float floatx4 __attribute__((ext_vector_type(4)));
typedef int   intx4  __attribute__((ext_vector_type(4)));
typedef int   intx8  __attribute__((ext_vector_type(8)));

#define MB ((size_t)1 << 20)

// async global->LDS, 16B per lane. LDS dest must be wave-uniform base + lane*16.
static __device__ __forceinline__ void async_load16(const void* g, void* l) {
    __builtin_amdgcn_global_load_lds(
        (const __attribute__((address_space(1))) uint32_t*)(uintptr_t)g,
        (__attribute__((address_space(3))) uint32_t*)(uint32_t)(uintptr_t)l,
        16, 0, 0);
}

// OCP e4m3 RNE saturating cast (HW cvt on gfx950 via hip_fp8.h)
static __device__ __forceinline__ uint8_t to_fp8(float v) {
    __hip_fp8_e4m3 h(v);
    return *reinterpret_cast<uint8_t*>(&h);
}

// ---------------- prep kernels (all reductions fixed-order — deterministic) --------

// merged: [0,8192)      cast x->fp8 (one row/block) + exact fp32 row sums S[n]
//         [8192,10240)  transpose wq/wk -> fp8 into wcat8 rows [0,2048)
//         [10240,10496) colsum stage1 partials
__global__ void prep_many(const float* __restrict__ x, uint8_t* __restrict__ x8,
                          float* __restrict__ Srow,
                          const float* __restrict__ wq, const float* __restrict__ wk,
                          uint8_t* __restrict__ wcat8, const float* __restrict__ wv,
                          float* __restrict__ part) {
    __shared__ float tile[32][33];
    __shared__ float wsum[4];
    const int bid = blockIdx.x, t = threadIdx.x;
    if (bid < 8192) {
        // one token row: cast 1024 floats -> fp8, and S[row] = exact fixed-order sum
        int i = bid * 256 + t;
        float4 v = ((const float4*)x)[i];
        uint32_t pk = (uint32_t)to_fp8(v.x) | ((uint32_t)to_fp8(v.y) << 8) |
                      ((uint32_t)to_fp8(v.z) << 16) | ((uint32_t)to_fp8(v.w) << 24);
        ((uint32_t*)x8)[i] = pk;
        float s = (v.x + v.y) + (v.z + v.w);
        #pragma unroll
        for (int d = 1; d < 64; d <<= 1) s += __shfl_xor(s, d);
        if ((t & 63) == 0) wsum[t >> 6] = s;
        __syncthreads();
        if (t == 0) Srow[bid] = (wsum[0] + wsum[1]) + (wsum[2] + wsum[3]);
    } else if (bid < 10240) {
        int b2 = bid - 8192;
        const float* W = (b2 >= 1024) ? wk : wq;
        uint8_t* outp = wcat8 + (size_t)(b2 >> 10) * 1024 * 1024;
        int b3 = b2 & 1023;
        int c0 = (b3 & 31) * 32, r0 = (b3 >> 5) * 32;
        int tx = t & 31, ty = t >> 5;
        #pragma unroll
        for (int i = 0; i < 4; i++)
            tile[ty + i * 8][tx] = W[(r0 + ty + i * 8) * 1024 + c0 + tx];
        __syncthreads();
        #pragma unroll
        for (int i = 0; i < 4; i++)
            outp[(long)(c0 + ty + i * 8) * 1024 + r0 + tx] = to_fp8(tile[tx][ty + i * 8]);
    } else {
        int b = bid - 10240;            // 0..255
        int d = (b & 3) * 256 + t;
        int g = b >> 2;                 // 0..63
        float s = 0.f;
        #pragma unroll
        for (int i = 0; i < 16; i++) s += __expf(wv[(g * 16 + i) * 1024 + d]);
        part[g * 1024 + d] = s;
    }
}

// cs[d] = sum_g part[g][d], fixed g order
__global__ void colsum_stage2(const float* __restrict__ part, float* __restrict__ cs) {
    int d = blockIdx.x * 256 + threadIdx.x;    // gridDim.x = 4
    float s = 0.f;
    #pragma unroll 8
    for (int g = 0; g < 64; g++) s += part[g * 1024 + d];
    cs[d] = s;
}

// delta8[e][d] = fp8( 16 * (1024*exp(wv[e,d])/cs[d] - 1) )  — the deviation of
// 2^20*wv_stoch from its rank-1 mean, scaled x16 into fp8 normal range.
__global__ void prep_delta(const float* __restrict__ wv, const float* __restrict__ cs,
                           uint8_t* __restrict__ delta8) {
    int idx = blockIdx.x * 256 + threadIdx.x;  // 4096 blocks
    int d = idx & 1023;
    float r = __expf(wv[idx]) * 1024.0f / cs[d] - 1.0f;
    delta8[idx] = to_fp8(r * 16.0f);
}

// L[z*2048+col] = sum_{y=0..15} Lpart[(z*16+y)*2048 + col], fixed y order
__global__ void reduce_L(const float* __restrict__ Lpart, float* __restrict__ L) {
    int i = blockIdx.x * 256 + threadIdx.x;    // 32 blocks -> 8192
    int z = i >> 11, col = i & 2047;
    float s = 0.f;
    #pragma unroll
    for (int y = 0; y < 16; y++) s += Lpart[(z * 16 + y) * 2048 + col];
    L[i] = s;
}

// vpT[b][e][m] = fp8( vp[b*2048+m][e] * 2^30 / L[b*2048+m] )
// vp itself stays RAW bf16 for pass-B's "- v" epilogue.
__global__ void scale_transpose_vp(const bf16_t* __restrict__ vp,
                                   const float* __restrict__ L,
                                   uint8_t* __restrict__ vpT) {
    __shared__ float tile[32][33];
    __shared__ float ls[32];
    int t = threadIdx.x;
    int tx = t & 31, ty = t >> 5;
    int e0 = blockIdx.x * 32;   // 32
    int m0 = blockIdx.y * 32;   // 256 (global token)
    if (t < 32) ls[t] = 1073741824.0f / L[m0 + t];   // 2^30/L (2^30 exact, undone in pass B)
    __syncthreads();
    #pragma unroll
    for (int i = 0; i < 4; i++) {
        int mr = ty + i * 8;
        tile[mr][tx] = (float)vp[(long)(m0 + mr) * 1024 + e0 + tx] * ls[mr];
    }
    __syncthreads();
    int b = m0 >> 11, ml = m0 & 2047;
    #pragma unroll
    for (int i = 0; i < 4; i++)
        vpT[((long)(b * 1024 + e0 + ty + i * 8)) * 2048 + ml + tx] = to_fp8(tile[tx][ty + i * 8]);
}

// ---------------- MX-fp8 NT GEMM: C = A[M,K] * B[N,K]^T, K-step 128 ----------------
// A,B fp8 e4m3, unit scales (0x7f = 2^0). Tile 128x128, 128 B/row LDS with the
// c^(r&7) chunk swizzle (2-way bank aliasing, free). Fragment: 32 bytes/lane,
// A[m=lane&15][k=(lane>>4)*32 + j] — r5-verified end-to-end.
// XCD-locality: blockIdx.x is the M(row)-tile, blockIdx.y the N(col)-tile. With
// gridDim.x a multiple of 8, blocks sharing an A-strip satisfy l % 8 == by % 8,
// i.e. land on one XCD under round-robin dispatch -> strip stays in that L2.
// EPI 0: merged QKV: col-tile>>3 selects {q8 fp8, k8 fp8, v bf16}. v epilogue
//        applies the rank-1 reconstruction: v = acc*2^-24 + S[row]*2^-20.
// EPI 2: p = exp2(acc*scaleExp); store fp8 P; deterministic per-block column sums
//        -> Lpart[(z*16+by)*2048 + col] (no atomics)
// EPI 3: store f32: acc*2^-30 - Vp[row,col]   (Vp = raw bf16 v)
template <int EPI>
__global__ __launch_bounds__(256, 3) void gemm_nt_fp8(
    const uint8_t* __restrict__ A, const uint8_t* __restrict__ B, void* __restrict__ C,
    uint8_t* __restrict__ C1, bf16_t* __restrict__ Cv, const float* __restrict__ Srow,
    float* __restrict__ Lout, const bf16_t* __restrict__ Vp,
    int N, int K, long aBatch, long bBatch, long cBatch, float scaleExp)
{
    __shared__ __align__(16) uint8_t ldsA[128 * 128];
    __shared__ __align__(16) uint8_t ldsB[128 * 128];
    const int t = threadIdx.x;
    const int z = blockIdx.z;
    const int by = blockIdx.x;              // M(row)-tile  [XCD-locality swap]
    const int bx = blockIdx.y;              // N(col)-tile
    const uint8_t* Ab = A + (long)z * aBatch + (long)by * 128 * K;
    const uint8_t* Bb = B + (long)z * bBatch + (long)bx * 128 * K;
    const int r  = t >> 3;                  // 0..31 (row within 32-row staging group)
    const int cg = (t & 7) ^ (r & 7);       // global chunk for LDS slot t&7
    const uint8_t* ag0 = Ab + (long)r * K + cg * 16;
    const uint8_t* bg0 = Bb + (long)r * K + cg * 16;
    uint8_t* la = ldsA + t * 16;
    uint8_t* lb = ldsB + t * 16;
    const int lane = t & 63, wave = t >> 6;
    const int wm = (wave >> 1) * 64, wn = (wave & 1) * 64;
    const int fr = lane & 15;
    const int q4 = lane >> 4;               // k-group: k in [32*q4, 32*q4+32)
    const int sw = fr & 7;

    floatx4 zero = {0.f, 0.f, 0.f, 0.f};
    floatx4 acc[4][4];
    #pragma unroll
    for (int i = 0; i < 4; i++)
        #pragma unroll
        for (int j = 0; j < 4; j++) acc[i][j] = zero;

    for (int k0 = 0; k0 < K; k0 += 128) {
        __syncthreads();
        #pragma unroll
        for (int i = 0; i < 4; i++) {
            async_load16(ag0 + (long)(32 * i) * K + k0, la + 4096 * i);
            async_load16(bg0 + (long)(32 * i) * K + k0, lb + 4096 * i);
        }
        __syncthreads();
        intx8 af[4], bfr[4];
        #pragma unroll
        for (int i = 0; i < 4; i++) {
            int row = wm + i * 16 + fr;
            intx4 lo = *(const intx4*)(ldsA + row * 128 + ((2 * q4) ^ sw) * 16);
            intx4 hi = *(const intx4*)(ldsA + row * 128 + ((2 * q4 + 1) ^ sw) * 16);
            af[i][0] = lo[0]; af[i][1] = lo[1]; af[i][2] = lo[2]; af[i][3] = lo[3];
            af[i][4] = hi[0]; af[i][5] = hi[1]; af[i][6] = hi[2]; af[i][7] = hi[3];
        }
        #pragma unroll
        for (int j = 0; j < 4; j++) {
            int row = wn + j * 16 + fr;
            intx4 lo = *(const intx4*)(ldsB + row * 128 + ((2 * q4) ^ sw) * 16);
            intx4 hi = *(const intx4*)(ldsB + row * 128 + ((2 * q4 + 1) ^ sw) * 16);
            bfr[j][0] = lo[0]; bfr[j][1] = lo[1]; bfr[j][2] = lo[2]; bfr[j][3] = lo[3];
            bfr[j][4] = hi[0]; bfr[j][5] = hi[1]; bfr[j][6] = hi[2]; bfr[j][7] = hi[3];
        }
        #pragma unroll
        for (int i = 0; i < 4; i++)
            #pragma unroll
            for (int j = 0; j < 4; j++)
                acc[i][j] = __builtin_amdgcn_mfma_scale_f32_16x16x128_f8f6f4(
                    af[i], bfr[j], acc[i][j], 0, 0,      // cbsz=fp8, blgp=fp8
                    0, 0x7f7f7f7f, 0, 0x7f7f7f7f);       // unit scales (e8m0 bias 127)
    }

    // C/D layout: col = lane&15, row = (lane>>4)*4 + reg (shape-determined, dtype-indep)
    const int rq = (lane >> 4) * 4;
    const long rowBase = (long)by * 128 + wm;
    const int colBase = bx * 128 + wn;

    if constexpr (EPI == 0) {
        const int sel = bx >> 3;                      // 0=q8, 1=k8, 2=v(bf16)
        const int cB = (bx & 7) * 128 + wn;
        if (sel == 2) {
            const float c24 = 5.9604644775390625e-08f;   // 2^-24 (acc holds 16*sum(x*delta))
            const float c20 = 9.5367431640625e-07f;      // 2^-20
            #pragma unroll
            for (int mi = 0; mi < 4; mi++)
                #pragma unroll
                for (int rr = 0; rr < 4; rr++) {
                    long row = rowBase + mi * 16 + rq + rr;
                    float sv = Srow[row] * c20;
                    #pragma unroll
                    for (int ni = 0; ni < 4; ni++)
                        Cv[row * 1024 + cB + ni * 16 + fr] =
                            (bf16_t)(acc[mi][ni][rr] * c24 + sv);
                }
        } else {
            uint8_t* Cb = sel ? C1 : (uint8_t*)C;
            #pragma unroll
            for (int mi = 0; mi < 4; mi++)
                #pragma unroll
                for (int rr = 0; rr < 4; rr++) {
                    long row = rowBase + mi * 16 + rq + rr;
                    #pragma unroll
                    for (int ni = 0; ni < 4; ni++)
                        Cb[row * 1024 + cB + ni * 16 + fr] = to_fp8(acc[mi][ni][rr]);
                }
        }
    } else if constexpr (EPI == 2) {
        uint8_t* Cb = (uint8_t*)C + (long)z * cBatch;
        float csum[4] = {0.f, 0.f, 0.f, 0.f};
        #pragma unroll
        for (int mi = 0; mi < 4; mi++)
            #pragma unroll
            for (int rr = 0; rr < 4; rr++) {
                long row = rowBase + mi * 16 + rq + rr;
                #pragma unroll
                for (int ni = 0; ni < 4; ni++) {
                    // scaleExp carries log2(e) pre-folded: exp(s*a) == exp2(s*a*log2e)
                    float p = __builtin_amdgcn_exp2f(acc[mi][ni][rr] * scaleExp);
                    Cb[row * N + colBase + ni * 16 + fr] = to_fp8(p);
                    csum[ni] += p;
                }
            }
        float red[4];
        #pragma unroll
        for (int ni = 0; ni < 4; ni++) {
            float v = csum[ni];
            v += __shfl_xor(v, 16);
            v += __shfl_xor(v, 32);
            red[ni] = v;
        }
        __syncthreads();
        float* lf = (float*)ldsA;             // [2][128]: half (wm>>6) x column
        #pragma unroll
        for (int ni = 0; ni < 4; ni++)
            if (lane < 16)
                lf[(wm >> 6) * 128 + wn + ni * 16 + lane] = red[ni];
        __syncthreads();
        if (t < 128) {
            float s = lf[t] + lf[128 + t];
            Lout[(long)(z * 16 + by) * 2048 + bx * 128 + t] = s;
        }
    } else {  // EPI == 3
        float* Co = (float*)C + (long)z * cBatch;
        const bf16_t* Vb = Vp + (long)z * cBatch;
        const float inv230 = 9.313225746154785e-10f;   // 2^-30 exact
        #pragma unroll
        for (int mi = 0; mi < 4; mi++)
            #pragma unroll
            for (int rr = 0; rr < 4; rr++) {
                long row = rowBase + mi * 16 + rq + rr;
                #pragma unroll
                for (int ni = 0; ni < 4; ni++) {
                    int col = colBase + ni * 16 + fr;
                    Co[row * N + col] = acc[mi][ni][rr] * inv230 - (float)Vb[row * N + col];
                }
            }
    }
}

// ---------------- launch ----------------

extern "C" void kernel_launch(void* const* d_in, const int* in_sizes, int n_in,
                              void* d_out, int out_size, void* d_ws, size_t ws_size,
                              hipStream_t stream) {
    // setup_inputs order: x, wk, wq, wv
    const float* x  = (const float*)d_in[0];
    const float* wk = (const float*)d_in[1];
    const float* wq = (const float*)d_in[2];
    const float* wv = (const float*)d_in[3];
    float* out = (float*)d_out;

    char* ws = (char*)d_ws;
    // Workspace (~81 MB), lifetime-overlapped:
    //   [0,8M)    x8 fp8 (dead after QKV)
    //   [8,11M)   wcat8 = [wq8T|wk8T|16*delta8] (dead after QKV) -> P fp8 [0,16M)
    //   [32,33M)  wvpart (dead after colsum2) -> [32,40M) q8 (dead after A) -> vpT
    //   [48,56M)  k8 fp8
    //   [64,80M)  vp bf16 (raw v; pass-B epilogue subtracts it)
    //   [80M) cs (4KB); [80M+16K) Srow (32KB); [80M+64K) Lpart (512KB); [80M+576K) L (32KB)
    uint8_t* x8     = (uint8_t*)(ws + 0);
    uint8_t* wcat8  = (uint8_t*)(ws + 8 * MB);
    uint8_t* delta8 = wcat8 + 2u * 1024 * 1024;
    uint8_t* P      = (uint8_t*)(ws + 0);
    float*   wvpart = (float*)(ws + 32 * MB);
    uint8_t* q8     = (uint8_t*)(ws + 32 * MB);
    uint8_t* vpT    = (uint8_t*)(ws + 32 * MB);
    uint8_t* k8     = (uint8_t*)(ws + 48 * MB);
    bf16_t*  vp     = (bf16_t*)(ws + 64 * MB);
    float*   cs     = (float*)(ws + 80 * MB);
    float*   Srow   = (float*)(ws + 80 * MB + 16 * 1024);
    float*   Lpart  = (float*)(ws + 80 * MB + 64 * 1024);   // 131072 floats
    float*   L      = (float*)(ws + 80 * MB + 576 * 1024);  // 8192 floats

    const float scaleExp2 = 0.0318793572f;  // 2048^-0.5 * log2(e)

    // prep: cast x->fp8 + row sums S, transpose wq/wk->fp8, colsum partials
    prep_many<<<10496, 256, 0, stream>>>(x, x8, Srow, wq, wk, wcat8, wv, wvpart);
    colsum_stage2<<<4, 256, 0, stream>>>(wvpart, cs);
    prep_delta<<<4096, 256, 0, stream>>>(wv, cs, delta8);

    // merged QKV (MX-fp8): [q8|k8|16*sum(x*delta)] = x8 @ wcat8^T
    // v reconstructed in epilogue: v = acc*2^-24 + S[row]*2^-20  (bf16)
    gemm_nt_fp8<0><<<dim3(64, 24, 1), 256, 0, stream>>>(x8, wcat8, q8,
        k8, vp, Srow, nullptr, nullptr, 1024, 1024, 0, 0, 0, 0.f);

    // pass A (MX-fp8): P[b,n,m] = fp8(exp2(scale' * q.k)), col sums -> Lpart
    gemm_nt_fp8<2><<<dim3(16, 16, 4), 256, 0, stream>>>(q8, k8, P,
        nullptr, nullptr, nullptr, Lpart, nullptr, 2048, 1024,
        (long)2048 * 1024, (long)2048 * 1024, (long)2048 * 2048, scaleExp2);

    // L = fixed-order sum of the 16 per-block partials
    reduce_L<<<32, 256, 0, stream>>>(Lpart, L);

    // vpT = fp8(v * 2^30 / L) transposed; vp stays raw
    scale_transpose_vp<<<dim3(32, 256), 256, 0, stream>>>(vp, L, vpT);

    // pass B (MX-fp8): out[b,n,e] = (P @ vpT^T)*2^-30 - v[n,e]
    gemm_nt_fp8<3><<<dim3(16, 8, 4), 256, 0, stream>>>(P, vpT, out,
        nullptr, nullptr, nullptr, nullptr, vp, 1024, 2048,
        (long)2048 * 2048, (long)1024 * 2048, (long)2048 * 1024, 0.f);
}